// Round 5
// baseline (661.805 us; speedup 1.0000x reference)
//
#include <hip/hip_runtime.h>

typedef unsigned short u16;
typedef unsigned int   u32;
typedef __attribute__((ext_vector_type(8))) short  short8;
typedef __attribute__((ext_vector_type(4))) float  f32x4;
typedef __attribute__((ext_vector_type(2))) float  f32x2;
typedef __attribute__((ext_vector_type(2))) unsigned int u32v2;
typedef __attribute__((ext_vector_type(4))) unsigned int u32v4;

#define NN 50000
#define NE 800000

__device__ __forceinline__ float bf2f(u16 b) { return __uint_as_float(((u32)b) << 16); }
__device__ __forceinline__ float bflo(u32 p) { return __uint_as_float(p << 16); }
__device__ __forceinline__ float bfhi(u32 p) { return __uint_as_float(p & 0xffff0000u); }
__device__ __forceinline__ u16 f2bf(float f) {
    u32 u = __float_as_uint(f);
    u32 r = u + 0x7fffu + ((u >> 16) & 1u);
    return (u16)(r >> 16);
}
// leaky-relu + clamped exp (clamp is identity for this data's logit range)
__device__ __forceinline__ float lexp(float v) {
    v = fmaxf(v, 0.2f * v);
    return __expf(fminf(v, 60.f));
}

// ---------------------------------------------------------------------------
// dtype detection (parallel): flag 0=bf16, 1=fp32, 2=all-zero
// ---------------------------------------------------------------------------
struct DetectArgs { const u32* p[13]; int nw[13]; };

__global__ __launch_bounds__(256) void k_detect(DetectArgs a, int* flags) {
    __shared__ int sh[256], sz[256];
    int j = blockIdx.x;
    const u32* x = a.p[j];
    int n = a.nw[j];
    int t = threadIdx.x;
    int hits = 0, nz = 0;
    for (int i = t; i < n; i += 256) {
        u32 w = x[i];
        if (w) {
            ++nz;
            u32 e = (w >> 7) & 0xffu;
            if (e >= 100 && e <= 150) ++hits;
        }
    }
    sh[t] = hits; sz[t] = nz;
    __syncthreads();
    for (int ofs = 128; ofs > 0; ofs >>= 1) {
        if (t < ofs) { sh[t] += sh[t + ofs]; sz[t] += sz[t + ofs]; }
        __syncthreads();
    }
    if (t == 0) flags[j] = (sz[0] == 0) ? 2 : ((sh[0] * 2 >= sz[0]) ? 0 : 1);
}

// convert ONLY the 9 small attention params (al/ar/b x 3 layers) to fp32.
struct ConvArgs { const void* s[9]; float* d[9]; int n[9]; int fi[9]; };

__global__ void k_convert(ConvArgs a, const int* __restrict__ flags) {
    int j = blockIdx.y;
    int i = blockIdx.x * 256 + threadIdx.x;
    if (i >= a.n[j]) return;
    int fl = flags[a.fi[j]];
    float v = 0.f;
    if (fl == 1) v = ((const float*)a.s[j])[i];
    else if (fl == 0) v = bf2f(((const u16*)a.s[j])[i]);
    a.d[j][i] = v;
}

// pack W[K=256][N] into MFMA B-fragment order:
// chunk id = (nt*8 + kt)*64 + L holds 8 bf16: W[kt*32 + (L>>4)*8 + j][nt*16 + (L&15)]
__global__ void k_wpack(const void* __restrict__ Wsrc, const int* __restrict__ flags,
                        int fidx, int N, u16* __restrict__ Wp, int nchunks) {
    int id = blockIdx.x * 256 + threadIdx.x;
    if (id >= nchunks) return;
    int L = id & 63, kt = (id >> 6) & 7, nt = id >> 9;
    int col = nt * 16 + (L & 15);
    int krow = kt * 32 + ((L >> 4) & 3) * 8;
    bool isf32 = (flags[fidx] == 1);
#pragma unroll
    for (int j = 0; j < 8; ++j) {
        int s = (krow + j) * N + col;
        Wp[id * 8 + j] = isf32 ? f2bf(((const float*)Wsrc)[s]) : ((const u16*)Wsrc)[s];
    }
}

// ---------------------------------------------------------------------------
// CSR build (graph static across layers) — 3-phase multi-block scan
// ---------------------------------------------------------------------------
__global__ void k_hist(const int* __restrict__ dst, int* __restrict__ deg, int E) {
    int e = blockIdx.x * 256 + threadIdx.x;
    if (e < E) atomicAdd(&deg[dst[e]], 1);
}

__global__ __launch_bounds__(256) void k_scan_partial(const int* __restrict__ deg,
                                                      int* __restrict__ bsum, int n) {
    __shared__ int red[256];
    int t = threadIdx.x;
    int i = blockIdx.x * 256 + t;
    red[t] = (i < n) ? deg[i] : 0;
    __syncthreads();
    for (int ofs = 128; ofs > 0; ofs >>= 1) {
        if (t < ofs) red[t] += red[t + ofs];
        __syncthreads();
    }
    if (t == 0) bsum[blockIdx.x] = red[0];
}

__global__ __launch_bounds__(256) void k_scan_bsum(int* __restrict__ bsum, int nb) {
    __shared__ int s[256];
    int t = threadIdx.x;
    int v = (t < nb) ? bsum[t] : 0;
    s[t] = v;
    __syncthreads();
    for (int ofs = 1; ofs < 256; ofs <<= 1) {
        int x = (t >= ofs) ? s[t - ofs] : 0;
        __syncthreads();
        s[t] += x;
        __syncthreads();
    }
    if (t < nb) bsum[t] = s[t] - v;   // exclusive
}

__global__ __launch_bounds__(256) void k_scan_final(const int* __restrict__ deg,
                                                    const int* __restrict__ bsum,
                                                    int* __restrict__ rowptr,
                                                    int* __restrict__ cursor, int n) {
    __shared__ int s[256];
    int t = threadIdx.x;
    int i = blockIdx.x * 256 + t;
    int v = (i < n) ? deg[i] : 0;
    s[t] = v;
    __syncthreads();
    for (int ofs = 1; ofs < 256; ofs <<= 1) {
        int x = (t >= ofs) ? s[t - ofs] : 0;
        __syncthreads();
        s[t] += x;
        __syncthreads();
    }
    int excl = bsum[blockIdx.x] + s[t] - v;
    if (i < n) {
        rowptr[i] = excl;
        cursor[i] = excl;
        if (i == n - 1) rowptr[n] = excl + v;
    }
}

__global__ void k_scatter(const int* __restrict__ src, const int* __restrict__ dst,
                          int* __restrict__ cursor, int* __restrict__ csr_src, int E) {
    int e = blockIdx.x * 256 + threadIdx.x;
    if (e >= E) return;
    int p = atomicAdd(&cursor[dst[e]], 1);
    csr_src[p] = src[e];
}

// ---------------------------------------------------------------------------
// MFMA GEMM: [nrows,256] x Wp(packed bf16) -> bf16 featT (HEAD-MAJOR:
// featT[h][row][32]) so each head slice is a contiguous 3.2MB block ->
// one XCD's L2 holds its slice (r4: FETCH 338->33MB, verified).
// As staging XOR-swizzled (bank-conflict fix, r2).
// ---------------------------------------------------------------------------
__global__ __launch_bounds__(256) void k_gemm_mfma(const void* __restrict__ Xv,
                                                   const int* __restrict__ xflag,
                                                   const u16* __restrict__ Wp,
                                                   u16* __restrict__ OUT, int nrows) {
    __shared__ u16 As[64 * 256];   // 32 KB
    const int t = threadIdx.x;
    const int w = t >> 6, L = t & 63;
    const int quad = (L >> 4) & 3;
    const int r0 = blockIdx.x * 64;
    const int nb = blockIdx.y * 8;
    const bool xf32 = (xflag != nullptr) && (*xflag == 1);

    short8* Asv = (short8*)As;
    short8 zero = {0, 0, 0, 0, 0, 0, 0, 0};
#pragma unroll
    for (int i = 0; i < 8; ++i) {
        int g = i * 256 + t;
        int row = g >> 5, cc = g & 31;
        int r = r0 + row;
        short8 val = zero;
        if (r < nrows) {
            if (xf32) {
                const f32x4* Xf4 = (const f32x4*)Xv;
                f32x4 lo = Xf4[(size_t)r * 64 + cc * 2];
                f32x4 hi = Xf4[(size_t)r * 64 + cc * 2 + 1];
                val[0] = (short)f2bf(lo[0]); val[1] = (short)f2bf(lo[1]);
                val[2] = (short)f2bf(lo[2]); val[3] = (short)f2bf(lo[3]);
                val[4] = (short)f2bf(hi[0]); val[5] = (short)f2bf(hi[1]);
                val[6] = (short)f2bf(hi[2]); val[7] = (short)f2bf(hi[3]);
            } else {
                val = ((const short8*)Xv)[(size_t)r * 32 + cc];
            }
        }
        Asv[cc * 64 + (row ^ (cc & 7))] = val;
    }

    const short8* Wv = (const short8*)Wp;
    short8 bf[2][8];
#pragma unroll
    for (int jn = 0; jn < 2; ++jn) {
        int nt = nb + w + jn * 4;
#pragma unroll
        for (int kt = 0; kt < 8; ++kt) bf[jn][kt] = Wv[(nt * 8 + kt) * 64 + L];
    }
    __syncthreads();

    f32x4 acc[4][2];
#pragma unroll
    for (int mi = 0; mi < 4; ++mi)
#pragma unroll
        for (int jn = 0; jn < 2; ++jn) acc[mi][jn] = (f32x4){0.f, 0.f, 0.f, 0.f};

#pragma unroll
    for (int kt = 0; kt < 8; ++kt) {
        const int ccr = kt * 4 + quad;
#pragma unroll
        for (int mi = 0; mi < 4; ++mi) {
            short8 af = Asv[ccr * 64 + ((mi * 16 + (L & 15)) ^ (ccr & 7))];
            acc[mi][0] = __builtin_amdgcn_mfma_f32_16x16x32_bf16(af, bf[0][kt], acc[mi][0], 0, 0, 0);
            acc[mi][1] = __builtin_amdgcn_mfma_f32_16x16x32_bf16(af, bf[1][kt], acc[mi][1], 0, 0, 0);
        }
    }

    const int colbase = blockIdx.y * 128;
#pragma unroll
    for (int mi = 0; mi < 4; ++mi) {
        int rb = r0 + mi * 16 + quad * 4;
#pragma unroll
        for (int jn = 0; jn < 2; ++jn) {
            int c = colbase + (w + jn * 4) * 16 + (L & 15);
            const size_t hb = (size_t)(c >> 5) * nrows * 32 + (c & 31);
#pragma unroll
            for (int reg = 0; reg < 4; ++reg) {
                int r = rb + reg;
                if (r < nrows) OUT[hb + (size_t)r * 32] = f2bf(acc[mi][jn][reg]);
            }
        }
    }
}

// MFMA GEMM layer 2: [nrows,256](bf16) x Wp2 -> bf16 [nrows,32] (node-major;
// single head, no slicing downstream). BM=128, BN=32.
__global__ __launch_bounds__(256) void k_gemm_mfma32(const u16* __restrict__ Xb,
                                                     const u16* __restrict__ Wp,
                                                     u16* __restrict__ OUT, int nrows) {
    __shared__ u16 As[128 * 256];  // 64 KB
    const int t = threadIdx.x;
    const int w = t >> 6, L = t & 63;
    const int quad = (L >> 4) & 3;
    const int r0 = blockIdx.x * 128;
    const int mh = (w >> 1) * 64, nt = w & 1;

    const short8* Xv = (const short8*)Xb;
    short8* Asv = (short8*)As;
    short8 zero = {0, 0, 0, 0, 0, 0, 0, 0};
#pragma unroll
    for (int i = 0; i < 16; ++i) {
        int g = i * 256 + t;
        int row = g >> 5, cc = g & 31;
        int r = r0 + row;
        Asv[cc * 128 + (row ^ (cc & 7))] = (r < nrows) ? Xv[(size_t)r * 32 + cc] : zero;
    }

    const short8* Wv = (const short8*)Wp;
    short8 bf[8];
#pragma unroll
    for (int kt = 0; kt < 8; ++kt) bf[kt] = Wv[(nt * 8 + kt) * 64 + L];
    __syncthreads();

    f32x4 acc[4];
#pragma unroll
    for (int mi = 0; mi < 4; ++mi) acc[mi] = (f32x4){0.f, 0.f, 0.f, 0.f};

#pragma unroll
    for (int kt = 0; kt < 8; ++kt) {
        const int ccr = kt * 4 + quad;
#pragma unroll
        for (int mi = 0; mi < 4; ++mi) {
            short8 af = Asv[ccr * 128 + ((mh + mi * 16 + (L & 15)) ^ (ccr & 7))];
            acc[mi] = __builtin_amdgcn_mfma_f32_16x16x32_bf16(af, bf[kt], acc[mi], 0, 0, 0);
        }
    }

#pragma unroll
    for (int mi = 0; mi < 4; ++mi) {
        int rb = r0 + mh + mi * 16 + quad * 4;
        int c = nt * 16 + (L & 15);
#pragma unroll
        for (int reg = 0; reg < 4; ++reg) {
            int r = rb + reg;
            if (r < nrows) OUT[(size_t)r * 32 + c] = f2bf(acc[mi][reg]);
        }
    }
}

// attention logit dots, head-major feat: featT[h][node][32 bf16].
// writes elT/erT [8][N] (head-major, 200KB/slice -> L2-resident in gather)
__global__ void k_elr8(const u16* __restrict__ featT, const float* __restrict__ al,
                       const float* __restrict__ ar, float* __restrict__ elT,
                       float* __restrict__ erT, int n) {
    int node = blockIdx.x * 256 + threadIdx.x;
    int h = blockIdx.y;
    if (node >= n) return;
    const u32v4* fu = (const u32v4*)((const u32*)featT + ((size_t)h * n + node) * 16);
    const float* A = al + h * 32;
    const float* B = ar + h * 32;
    float sl = 0.f, sr = 0.f;
#pragma unroll
    for (int j = 0; j < 4; ++j) {
        u32v4 w4 = fu[j];
#pragma unroll
        for (int k = 0; k < 4; ++k) {
            u32 w = (k == 0) ? w4.x : (k == 1) ? w4.y : (k == 2) ? w4.z : w4.w;
            float f0 = bflo(w), f1 = bfhi(w);
            int c = j * 8 + k * 2;
            sl += f0 * A[c] + f1 * A[c + 1];
            sr += f0 * B[c] + f1 * B[c + 1];
        }
    }
    elT[(size_t)h * n + node] = sl;
    erT[(size_t)h * n + node] = sr;
}

__global__ void k_elr1(const u16* __restrict__ featb, const float* __restrict__ al,
                       const float* __restrict__ ar, float* __restrict__ el,
                       float* __restrict__ er, int n) {
    int node = blockIdx.x * 256 + threadIdx.x;
    if (node >= n) return;
    const u32v4* fu = (const u32v4*)((const u32*)featb + (size_t)node * 16);
    float sl = 0.f, sr = 0.f;
#pragma unroll
    for (int j = 0; j < 4; ++j) {
        u32v4 w4 = fu[j];
#pragma unroll
        for (int k = 0; k < 4; ++k) {
            u32 w = (k == 0) ? w4.x : (k == 1) ? w4.y : (k == 2) ? w4.z : w4.w;
            float f0 = bflo(w), f1 = bfhi(w);
            int c = j * 8 + k * 2;
            sl += f0 * al[c] + f1 * al[c + 1];
            sr += f0 * ar[c] + f1 * ar[c + 1];
        }
    }
    el[node] = sl;
    er[node] = sr;
}

// ---------------------------------------------------------------------------
// fused softmax+gather (r5): head-sliced + XCD-pinned (r4, keeps FETCH=33MB)
// + ONE NODE PER WAVE + LDS (s,exp) staging + 8-edge-parallel inner loop.
//
// r4 post-mortem: FETCH fixed (33MB) but dur 103us at 580GB/s -> NOT BW-
// bound; overhead-bound (2 dependent ds_bpermute per edge + ~8 VALU addr/
// unpack + 1.5x divergence from 4 nodes/wave). Floor ~15-20us.
// r5 structure: wave stages a 64-edge chunk into LDS (each lane: own csr/
// el/exp once -> ds_write_b64 pair), then ceil(nv/8) iterations; lane
// (j8=lane>>3, c8=lane&7): 1 broadcast ds_read_b64 gives (s,alpha) of edge
// i*8+j8, 1 u32v2 feat load (8 edges x 64B rows coalesced), 4 FMA. No
// bpermute, no divergence (exact per-node trip counts), all loads per
// chunk independent. Same-wave ds_write->ds_read is in-order on the DS
// pipe (wave-synchronous idiom); sched_barrier(0) pins compiler order.
// Tail lanes clamp csr (dedups to broadcast) and stage alpha=0.
// ---------------------------------------------------------------------------
__global__ __launch_bounds__(256) void k_gather8(const int* __restrict__ rowptr,
                                                 const int* __restrict__ csr_src,
                                                 const float* __restrict__ elT,
                                                 const float* __restrict__ erT,
                                                 const u32* __restrict__ featT2,
                                                 const float* __restrict__ bias,
                                                 u32* __restrict__ xout2) {
    __shared__ u32v2 sbuf[4][64];        // per-wave (s, exp) pairs, 2KB
    const int t = threadIdx.x;
    const int wv = t >> 6;
    const int lane = t & 63;
    const int h = blockIdx.x & 7;        // head slice == XCD (round-robin)
    const int d = (blockIdx.x >> 3) * 4 + wv;   // node: 12500*4 = 50000 exact
    const int j8 = lane >> 3, c8 = lane & 7;
    const int b = rowptr[d], e = rowptr[d + 1];
    const int deg = e - b;
    const float* __restrict__ elh = elT + (size_t)h * NN;
    const u32v2* __restrict__ fv = (const u32v2*)(featT2 + (size_t)h * NN * 16);
    const float erd = erT[(size_t)h * NN + d];
    u32v2* __restrict__ sb = sbuf[wv];

    float a0 = 0.f, a1 = 0.f, a2 = 0.f, a3 = 0.f, ssum = 0.f;

    for (int c = 0; c < deg; c += 64) {
        const int nv = deg - c < 64 ? deg - c : 64;
        const int idx = b + c + (lane < nv ? lane : nv - 1);
        const int s_own = __builtin_nontemporal_load(csr_src + idx);
        const float ex_own = (lane < nv) ? lexp(elh[s_own] + erd) : 0.f;
        ssum += ex_own;
        u32v2 pr;
        pr.x = (u32)s_own;
        pr.y = __float_as_uint(ex_own);
        sb[lane] = pr;
        __builtin_amdgcn_sched_barrier(0);
        const int ni = (nv + 7) >> 3;
        for (int i = 0; i < ni; ++i) {
            const u32v2 pr2 = sb[i * 8 + j8];          // 8-lane broadcast b64
            const float ai = __uint_as_float(pr2.y);
            const u32v2 w = fv[(size_t)pr2.x * 8 + c8]; // 8 edges x 64B rows
            a0 += bflo(w.x) * ai; a1 += bfhi(w.x) * ai;
            a2 += bflo(w.y) * ai; a3 += bfhi(w.y) * ai;
        }
        __builtin_amdgcn_sched_barrier(0);
    }

    // reduce edge-subset partials across j8 (bits 3..5)
    a0 += __shfl_xor(a0, 8); a0 += __shfl_xor(a0, 16); a0 += __shfl_xor(a0, 32);
    a1 += __shfl_xor(a1, 8); a1 += __shfl_xor(a1, 16); a1 += __shfl_xor(a1, 32);
    a2 += __shfl_xor(a2, 8); a2 += __shfl_xor(a2, 16); a2 += __shfl_xor(a2, 32);
    a3 += __shfl_xor(a3, 8); a3 += __shfl_xor(a3, 16); a3 += __shfl_xor(a3, 32);
    // denominator: full 64-lane reduce of staged exps
    ssum += __shfl_xor(ssum, 1);  ssum += __shfl_xor(ssum, 2);
    ssum += __shfl_xor(ssum, 4);  ssum += __shfl_xor(ssum, 8);
    ssum += __shfl_xor(ssum, 16); ssum += __shfl_xor(ssum, 32);

    if (j8 == 0) {
        const float rd = 1.f / (ssum + 1e-9f);
        const f32x4 bb = *(const f32x4*)&bias[h * 32 + c8 * 4];
        float v0 = a0 * rd + bb[0];
        float v1 = a1 * rd + bb[1];
        float v2 = a2 * rd + bb[2];
        float v3 = a3 * rd + bb[3];
        v0 = v0 > 0.f ? v0 : expm1f(v0);
        v1 = v1 > 0.f ? v1 : expm1f(v1);
        v2 = v2 > 0.f ? v2 : expm1f(v2);
        v3 = v3 > 0.f ? v3 : expm1f(v3);
        u32v2 o;
        o.x = (u32)f2bf(v0) | ((u32)f2bf(v1) << 16);
        o.y = (u32)f2bf(v2) | ((u32)f2bf(v3) << 16);
        __builtin_nontemporal_store(o, (u32v2*)xout2 + ((size_t)d * 64 + h * 8 + c8));
    }
}

// layer-2 fused gather: 16 lanes/node x u32 (2 cols/lane), 4 nodes/wave.
__global__ __launch_bounds__(256) void k_gather1(const int* __restrict__ rowptr,
                                                 const int* __restrict__ csr_src,
                                                 const float* __restrict__ el,
                                                 const float* __restrict__ er,
                                                 const u32* __restrict__ featb2,
                                                 const float* __restrict__ bias,
                                                 void* __restrict__ out,
                                                 const int* __restrict__ flag, int n) {
    int t = threadIdx.x;
    int d = blockIdx.x * 16 + (t >> 4);
    int q = t & 15;           // owns cols 2q, 2q+1
    if (d >= n) return;
    int b = rowptr[d], e = rowptr[d + 1];
    float erd = er[d];
    float a0 = 0.f, a1 = 0.f, ssum = 0.f;
    int p = b;
    for (; p + 4 <= e; p += 4) {
        int s0 = csr_src[p], s1 = csr_src[p + 1], s2 = csr_src[p + 2], s3 = csr_src[p + 3];
        float e0 = lexp(el[s0] + erd);
        float e1 = lexp(el[s1] + erd);
        float e2 = lexp(el[s2] + erd);
        float e3 = lexp(el[s3] + erd);
        u32 w0 = featb2[(size_t)s0 * 16 + q];
        u32 w1 = featb2[(size_t)s1 * 16 + q];
        u32 w2 = featb2[(size_t)s2 * 16 + q];
        u32 w3 = featb2[(size_t)s3 * 16 + q];
        a0 += bflo(w0) * e0; a1 += bfhi(w0) * e0;
        a0 += bflo(w1) * e1; a1 += bfhi(w1) * e1;
        a0 += bflo(w2) * e2; a1 += bfhi(w2) * e2;
        a0 += bflo(w3) * e3; a1 += bfhi(w3) * e3;
        ssum += (e0 + e1) + (e2 + e3);
    }
    for (; p < e; ++p) {
        int s = csr_src[p];
        float ev = lexp(el[s] + erd);
        u32 w = featb2[(size_t)s * 16 + q];
        a0 += bflo(w) * ev;
        a1 += bfhi(w) * ev;
        ssum += ev;
    }
    float rd = 1.f / (ssum + 1e-9f);
    float v0 = a0 * rd + bias[2 * q];
    float v1 = a1 * rd + bias[2 * q + 1];
    if (*flag == 1) {
        f32x2 o = {v0, v1};
        ((f32x2*)out)[(size_t)d * 16 + q] = o;
    } else {
        ((u32*)out)[(size_t)d * 16 + q] = (u32)f2bf(v0) | ((u32)f2bf(v1) << 16);
    }
}

extern "C" void kernel_launch(void* const* d_in, const int* in_sizes, int n_in,
                              void* d_out, int out_size, void* d_ws, size_t ws_size,
                              hipStream_t stream) {
    const void* features = d_in[0];
    const int* src = (const int*)d_in[1];
    const int* dst = (const int*)d_in[2];

    char* ws = (char*)d_ws;
    size_t off = 0;
    auto carve = [&](size_t bytes) -> void* {
        void* p = ws + off;
        off = (off + bytes + 255) & ~(size_t)255;
        return p;
    };
    int*   flags = (int*)carve(64);
    float* pconv = (float*)carve(2048 * 4);
    u16*   Wp0 = (u16*)carve(65536 * 2);
    u16*   Wp1 = (u16*)carve(65536 * 2);
    u16*   Wp2 = (u16*)carve(8192 * 2);
    u16*   Xb    = (u16*)carve((size_t)NN * 256 * 2);  // bf16 hidden state (node-major)
    u16*   featb = (u16*)carve((size_t)NN * 256 * 2);  // bf16 GEMM output (head-major)
    float* el   = (float*)carve((size_t)NN * 8 * 4);
    float* er   = (float*)carve((size_t)NN * 8 * 4);
    int*   deg     = (int*)carve((size_t)NN * 4);
    int*   cursor  = (int*)carve((size_t)NN * 4);
    int*   rowptr  = (int*)carve((size_t)(NN + 1) * 4);
    int*   bsum    = (int*)carve(256 * 4);
    int*   csr_src = (int*)carve((size_t)NE * 4);
    if (off > ws_size) return;  // clean ws-too-small signature

    const int N = NN, E = NE;
    const int nscan = (N + 255) / 256;   // 196 <= 256

    DetectArgs da;
    const int din_idx[13] = {0, 3, 4, 5, 6, 7, 8, 9, 10, 11, 12, 13, 14};
    for (int j = 0; j < 13; ++j) {
        da.p[j] = (const u32*)d_in[din_idx[j]];
        int nw = in_sizes[din_idx[j]] / 2;
        da.nw[j] = nw > 512 ? 512 : nw;
    }
    k_detect<<<13, 256, 0, stream>>>(da, flags);

    // 9 small params -> fp32
    ConvArgs ca;
    const int psl[9] = {4, 5, 6, 8, 9, 10, 12, 13, 14};
    const int pfl[9] = {2, 3, 4, 6, 7, 8, 10, 11, 12};
    float* dsts[9];
    {
        size_t o = 0;
        for (int j = 0; j < 9; ++j) {
            dsts[j] = pconv + o;
            o += (size_t)in_sizes[psl[j]];
        }
    }
    for (int j = 0; j < 9; ++j) {
        ca.s[j] = d_in[psl[j]];
        ca.d[j] = dsts[j];
        ca.n[j] = in_sizes[psl[j]];
        ca.fi[j] = pfl[j];
    }
    k_convert<<<dim3(1, 9), 256, 0, stream>>>(ca, flags);
    float* al0f = dsts[0]; float* ar0f = dsts[1]; float* b0f = dsts[2];
    float* al1f = dsts[3]; float* ar1f = dsts[4]; float* b1f = dsts[5];
    float* al2f = dsts[6]; float* ar2f = dsts[7]; float* b2f = dsts[8];

    // W packing into B-frag order (once)
    k_wpack<<<32, 256, 0, stream>>>(d_in[3],  flags, 1, 256, Wp0, 8192);
    k_wpack<<<32, 256, 0, stream>>>(d_in[7],  flags, 5, 256, Wp1, 8192);
    k_wpack<<<4,  256, 0, stream>>>(d_in[11], flags, 9, 32,  Wp2, 1024);

    // CSR build (multi-block scan)
    hipMemsetAsync(deg, 0, (size_t)N * 4, stream);
    k_hist<<<(E + 255) / 256, 256, 0, stream>>>(dst, deg, E);
    k_scan_partial<<<nscan, 256, 0, stream>>>(deg, bsum, N);
    k_scan_bsum<<<1, 256, 0, stream>>>(bsum, nscan);
    k_scan_final<<<nscan, 256, 0, stream>>>(deg, bsum, rowptr, cursor, N);
    k_scatter<<<(E + 255) / 256, 256, 0, stream>>>(src, dst, cursor, csr_src, E);

    const dim3 ggrid((N + 63) / 64, 2);
    const dim3 egrid(nscan, 8);          // elr8: nodes x heads
    const int ggrid8 = 8 * (N / 4);      // 8 head-slices x 12500 node-quads

    // ---------------- layer 0 (reads features directly, dtype via flag) ----
    k_gemm_mfma<<<ggrid, 256, 0, stream>>>(features, flags, Wp0, featb, N);
    k_elr8<<<egrid, 256, 0, stream>>>(featb, al0f, ar0f, el, er, N);
    k_gather8<<<ggrid8, 256, 0, stream>>>(rowptr, csr_src, el, er,
                                          (const u32*)featb, b0f, (u32*)Xb);

    // ---------------- layer 1 ----------------
    k_gemm_mfma<<<ggrid, 256, 0, stream>>>(Xb, nullptr, Wp1, featb, N);
    k_elr8<<<egrid, 256, 0, stream>>>(featb, al1f, ar1f, el, er, N);
    k_gather8<<<ggrid8, 256, 0, stream>>>(rowptr, csr_src, el, er,
                                          (const u32*)featb, b1f, (u32*)Xb);

    // ---------------- layer 2 (1 head, D=32) ----------------
    k_gemm_mfma32<<<(N + 127) / 128, 256, 0, stream>>>(Xb, Wp2, featb, N);
    k_elr1<<<(N + 255) / 256, 256, 0, stream>>>(featb, al2f, ar2f, el, er, N);
    k_gather1<<<(N + 15) / 16, 256, 0, stream>>>(rowptr, csr_src, el, er,
                                                 (const u32*)featb, b2f,
                                                 d_out, flags, N);
}

// Round 6
// 548.323 us; speedup vs baseline: 1.2070x; 1.2070x over previous
//
#include <hip/hip_runtime.h>

typedef unsigned short u16;
typedef unsigned int   u32;
typedef __attribute__((ext_vector_type(8))) short  short8;
typedef __attribute__((ext_vector_type(4))) float  f32x4;
typedef __attribute__((ext_vector_type(2))) float  f32x2;
typedef __attribute__((ext_vector_type(2))) unsigned int u32v2;
typedef __attribute__((ext_vector_type(4))) unsigned int u32v4;

#define NN 50000
#define NE 800000

__device__ __forceinline__ float bf2f(u16 b) { return __uint_as_float(((u32)b) << 16); }
__device__ __forceinline__ float bflo(u32 p) { return __uint_as_float(p << 16); }
__device__ __forceinline__ float bfhi(u32 p) { return __uint_as_float(p & 0xffff0000u); }
__device__ __forceinline__ u16 f2bf(float f) {
    u32 u = __float_as_uint(f);
    u32 r = u + 0x7fffu + ((u >> 16) & 1u);
    return (u16)(r >> 16);
}
// leaky-relu + clamped exp (clamp is identity for this data's logit range)
__device__ __forceinline__ float lexp(float v) {
    v = fmaxf(v, 0.2f * v);
    return __expf(fminf(v, 60.f));
}

// ---------------------------------------------------------------------------
// dtype detection (parallel): flag 0=bf16, 1=fp32, 2=all-zero
// ---------------------------------------------------------------------------
struct DetectArgs { const u32* p[13]; int nw[13]; };

__global__ __launch_bounds__(256) void k_detect(DetectArgs a, int* flags) {
    __shared__ int sh[256], sz[256];
    int j = blockIdx.x;
    const u32* x = a.p[j];
    int n = a.nw[j];
    int t = threadIdx.x;
    int hits = 0, nz = 0;
    for (int i = t; i < n; i += 256) {
        u32 w = x[i];
        if (w) {
            ++nz;
            u32 e = (w >> 7) & 0xffu;
            if (e >= 100 && e <= 150) ++hits;
        }
    }
    sh[t] = hits; sz[t] = nz;
    __syncthreads();
    for (int ofs = 128; ofs > 0; ofs >>= 1) {
        if (t < ofs) { sh[t] += sh[t + ofs]; sz[t] += sz[t + ofs]; }
        __syncthreads();
    }
    if (t == 0) flags[j] = (sz[0] == 0) ? 2 : ((sh[0] * 2 >= sz[0]) ? 0 : 1);
}

// convert ONLY the 9 small attention params (al/ar/b x 3 layers) to fp32.
struct ConvArgs { const void* s[9]; float* d[9]; int n[9]; int fi[9]; };

__global__ void k_convert(ConvArgs a, const int* __restrict__ flags) {
    int j = blockIdx.y;
    int i = blockIdx.x * 256 + threadIdx.x;
    if (i >= a.n[j]) return;
    int fl = flags[a.fi[j]];
    float v = 0.f;
    if (fl == 1) v = ((const float*)a.s[j])[i];
    else if (fl == 0) v = bf2f(((const u16*)a.s[j])[i]);
    a.d[j][i] = v;
}

// pack W[K=256][N] into MFMA B-fragment order:
// chunk id = (nt*8 + kt)*64 + L holds 8 bf16: W[kt*32 + (L>>4)*8 + j][nt*16 + (L&15)]
__global__ void k_wpack(const void* __restrict__ Wsrc, const int* __restrict__ flags,
                        int fidx, int N, u16* __restrict__ Wp, int nchunks) {
    int id = blockIdx.x * 256 + threadIdx.x;
    if (id >= nchunks) return;
    int L = id & 63, kt = (id >> 6) & 7, nt = id >> 9;
    int col = nt * 16 + (L & 15);
    int krow = kt * 32 + ((L >> 4) & 3) * 8;
    bool isf32 = (flags[fidx] == 1);
#pragma unroll
    for (int j = 0; j < 8; ++j) {
        int s = (krow + j) * N + col;
        Wp[id * 8 + j] = isf32 ? f2bf(((const float*)Wsrc)[s]) : ((const u16*)Wsrc)[s];
    }
}

// ---------------------------------------------------------------------------
// CSR build (graph static across layers) — 3-phase multi-block scan
// ---------------------------------------------------------------------------
__global__ void k_hist(const int* __restrict__ dst, int* __restrict__ deg, int E) {
    int e = blockIdx.x * 256 + threadIdx.x;
    if (e < E) atomicAdd(&deg[dst[e]], 1);
}

__global__ __launch_bounds__(256) void k_scan_partial(const int* __restrict__ deg,
                                                      int* __restrict__ bsum, int n) {
    __shared__ int red[256];
    int t = threadIdx.x;
    int i = blockIdx.x * 256 + t;
    red[t] = (i < n) ? deg[i] : 0;
    __syncthreads();
    for (int ofs = 128; ofs > 0; ofs >>= 1) {
        if (t < ofs) red[t] += red[t + ofs];
        __syncthreads();
    }
    if (t == 0) bsum[blockIdx.x] = red[0];
}

__global__ __launch_bounds__(256) void k_scan_bsum(int* __restrict__ bsum, int nb) {
    __shared__ int s[256];
    int t = threadIdx.x;
    int v = (t < nb) ? bsum[t] : 0;
    s[t] = v;
    __syncthreads();
    for (int ofs = 1; ofs < 256; ofs <<= 1) {
        int x = (t >= ofs) ? s[t - ofs] : 0;
        __syncthreads();
        s[t] += x;
        __syncthreads();
    }
    if (t < nb) bsum[t] = s[t] - v;   // exclusive
}

__global__ __launch_bounds__(256) void k_scan_final(const int* __restrict__ deg,
                                                    const int* __restrict__ bsum,
                                                    int* __restrict__ rowptr,
                                                    int* __restrict__ cursor, int n) {
    __shared__ int s[256];
    int t = threadIdx.x;
    int i = blockIdx.x * 256 + t;
    int v = (i < n) ? deg[i] : 0;
    s[t] = v;
    __syncthreads();
    for (int ofs = 1; ofs < 256; ofs <<= 1) {
        int x = (t >= ofs) ? s[t - ofs] : 0;
        __syncthreads();
        s[t] += x;
        __syncthreads();
    }
    int excl = bsum[blockIdx.x] + s[t] - v;
    if (i < n) {
        rowptr[i] = excl;
        cursor[i] = excl;
        if (i == n - 1) rowptr[n] = excl + v;
    }
}

__global__ void k_scatter(const int* __restrict__ src, const int* __restrict__ dst,
                          int* __restrict__ cursor, int* __restrict__ csr_src, int E) {
    int e = blockIdx.x * 256 + threadIdx.x;
    if (e >= E) return;
    int p = atomicAdd(&cursor[dst[e]], 1);
    csr_src[p] = src[e];
}

// ---------------------------------------------------------------------------
// MFMA GEMM: [nrows,256] x Wp(packed bf16) -> bf16 featT (HEAD-MAJOR:
// featT[h][row][32]) so each head slice is a contiguous 3.2MB block ->
// one XCD's L2 holds its slice (r4: FETCH 338->33MB, verified).
// As staging XOR-swizzled (bank-conflict fix, r2).
// ---------------------------------------------------------------------------
__global__ __launch_bounds__(256) void k_gemm_mfma(const void* __restrict__ Xv,
                                                   const int* __restrict__ xflag,
                                                   const u16* __restrict__ Wp,
                                                   u16* __restrict__ OUT, int nrows) {
    __shared__ u16 As[64 * 256];   // 32 KB
    const int t = threadIdx.x;
    const int w = t >> 6, L = t & 63;
    const int quad = (L >> 4) & 3;
    const int r0 = blockIdx.x * 64;
    const int nb = blockIdx.y * 8;
    const bool xf32 = (xflag != nullptr) && (*xflag == 1);

    short8* Asv = (short8*)As;
    short8 zero = {0, 0, 0, 0, 0, 0, 0, 0};
#pragma unroll
    for (int i = 0; i < 8; ++i) {
        int g = i * 256 + t;
        int row = g >> 5, cc = g & 31;
        int r = r0 + row;
        short8 val = zero;
        if (r < nrows) {
            if (xf32) {
                const f32x4* Xf4 = (const f32x4*)Xv;
                f32x4 lo = Xf4[(size_t)r * 64 + cc * 2];
                f32x4 hi = Xf4[(size_t)r * 64 + cc * 2 + 1];
                val[0] = (short)f2bf(lo[0]); val[1] = (short)f2bf(lo[1]);
                val[2] = (short)f2bf(lo[2]); val[3] = (short)f2bf(lo[3]);
                val[4] = (short)f2bf(hi[0]); val[5] = (short)f2bf(hi[1]);
                val[6] = (short)f2bf(hi[2]); val[7] = (short)f2bf(hi[3]);
            } else {
                val = ((const short8*)Xv)[(size_t)r * 32 + cc];
            }
        }
        Asv[cc * 64 + (row ^ (cc & 7))] = val;
    }

    const short8* Wv = (const short8*)Wp;
    short8 bf[2][8];
#pragma unroll
    for (int jn = 0; jn < 2; ++jn) {
        int nt = nb + w + jn * 4;
#pragma unroll
        for (int kt = 0; kt < 8; ++kt) bf[jn][kt] = Wv[(nt * 8 + kt) * 64 + L];
    }
    __syncthreads();

    f32x4 acc[4][2];
#pragma unroll
    for (int mi = 0; mi < 4; ++mi)
#pragma unroll
        for (int jn = 0; jn < 2; ++jn) acc[mi][jn] = (f32x4){0.f, 0.f, 0.f, 0.f};

#pragma unroll
    for (int kt = 0; kt < 8; ++kt) {
        const int ccr = kt * 4 + quad;
#pragma unroll
        for (int mi = 0; mi < 4; ++mi) {
            short8 af = Asv[ccr * 64 + ((mi * 16 + (L & 15)) ^ (ccr & 7))];
            acc[mi][0] = __builtin_amdgcn_mfma_f32_16x16x32_bf16(af, bf[0][kt], acc[mi][0], 0, 0, 0);
            acc[mi][1] = __builtin_amdgcn_mfma_f32_16x16x32_bf16(af, bf[1][kt], acc[mi][1], 0, 0, 0);
        }
    }

    const int colbase = blockIdx.y * 128;
#pragma unroll
    for (int mi = 0; mi < 4; ++mi) {
        int rb = r0 + mi * 16 + quad * 4;
#pragma unroll
        for (int jn = 0; jn < 2; ++jn) {
            int c = colbase + (w + jn * 4) * 16 + (L & 15);
            const size_t hb = (size_t)(c >> 5) * nrows * 32 + (c & 31);
#pragma unroll
            for (int reg = 0; reg < 4; ++reg) {
                int r = rb + reg;
                if (r < nrows) OUT[hb + (size_t)r * 32] = f2bf(acc[mi][jn][reg]);
            }
        }
    }
}

// MFMA GEMM layer 2: [nrows,256](bf16) x Wp2 -> bf16 [nrows,32] (node-major;
// single head, no slicing downstream). BM=128, BN=32.
__global__ __launch_bounds__(256) void k_gemm_mfma32(const u16* __restrict__ Xb,
                                                     const u16* __restrict__ Wp,
                                                     u16* __restrict__ OUT, int nrows) {
    __shared__ u16 As[128 * 256];  // 64 KB
    const int t = threadIdx.x;
    const int w = t >> 6, L = t & 63;
    const int quad = (L >> 4) & 3;
    const int r0 = blockIdx.x * 128;
    const int mh = (w >> 1) * 64, nt = w & 1;

    const short8* Xv = (const short8*)Xb;
    short8* Asv = (short8*)As;
    short8 zero = {0, 0, 0, 0, 0, 0, 0, 0};
#pragma unroll
    for (int i = 0; i < 16; ++i) {
        int g = i * 256 + t;
        int row = g >> 5, cc = g & 31;
        int r = r0 + row;
        Asv[cc * 128 + (row ^ (cc & 7))] = (r < nrows) ? Xv[(size_t)r * 32 + cc] : zero;
    }

    const short8* Wv = (const short8*)Wp;
    short8 bf[8];
#pragma unroll
    for (int kt = 0; kt < 8; ++kt) bf[kt] = Wv[(nt * 8 + kt) * 64 + L];
    __syncthreads();

    f32x4 acc[4];
#pragma unroll
    for (int mi = 0; mi < 4; ++mi) acc[mi] = (f32x4){0.f, 0.f, 0.f, 0.f};

#pragma unroll
    for (int kt = 0; kt < 8; ++kt) {
        const int ccr = kt * 4 + quad;
#pragma unroll
        for (int mi = 0; mi < 4; ++mi) {
            short8 af = Asv[ccr * 128 + ((mh + mi * 16 + (L & 15)) ^ (ccr & 7))];
            acc[mi] = __builtin_amdgcn_mfma_f32_16x16x32_bf16(af, bf[kt], acc[mi], 0, 0, 0);
        }
    }

#pragma unroll
    for (int mi = 0; mi < 4; ++mi) {
        int rb = r0 + mh + mi * 16 + quad * 4;
        int c = nt * 16 + (L & 15);
#pragma unroll
        for (int reg = 0; reg < 4; ++reg) {
            int r = rb + reg;
            if (r < nrows) OUT[(size_t)r * 32 + c] = f2bf(acc[mi][reg]);
        }
    }
}

// attention logit dots, head-major feat: featT[h][node][32 bf16].
// writes elT/erT [8][N] (head-major, 200KB/slice -> L2-resident in gather)
__global__ void k_elr8(const u16* __restrict__ featT, const float* __restrict__ al,
                       const float* __restrict__ ar, float* __restrict__ elT,
                       float* __restrict__ erT, int n) {
    int node = blockIdx.x * 256 + threadIdx.x;
    int h = blockIdx.y;
    if (node >= n) return;
    const u32v4* fu = (const u32v4*)((const u32*)featT + ((size_t)h * n + node) * 16);
    const float* A = al + h * 32;
    const float* B = ar + h * 32;
    float sl = 0.f, sr = 0.f;
#pragma unroll
    for (int j = 0; j < 4; ++j) {
        u32v4 w4 = fu[j];
#pragma unroll
        for (int k = 0; k < 4; ++k) {
            u32 w = (k == 0) ? w4.x : (k == 1) ? w4.y : (k == 2) ? w4.z : w4.w;
            float f0 = bflo(w), f1 = bfhi(w);
            int c = j * 8 + k * 2;
            sl += f0 * A[c] + f1 * A[c + 1];
            sr += f0 * B[c] + f1 * B[c + 1];
        }
    }
    elT[(size_t)h * n + node] = sl;
    erT[(size_t)h * n + node] = sr;
}

__global__ void k_elr1(const u16* __restrict__ featb, const float* __restrict__ al,
                       const float* __restrict__ ar, float* __restrict__ el,
                       float* __restrict__ er, int n) {
    int node = blockIdx.x * 256 + threadIdx.x;
    if (node >= n) return;
    const u32v4* fu = (const u32v4*)((const u32*)featb + (size_t)node * 16);
    float sl = 0.f, sr = 0.f;
#pragma unroll
    for (int j = 0; j < 4; ++j) {
        u32v4 w4 = fu[j];
#pragma unroll
        for (int k = 0; k < 4; ++k) {
            u32 w = (k == 0) ? w4.x : (k == 1) ? w4.y : (k == 2) ? w4.z : w4.w;
            float f0 = bflo(w), f1 = bfhi(w);
            int c = j * 8 + k * 2;
            sl += f0 * al[c] + f1 * al[c + 1];
            sr += f0 * ar[c] + f1 * ar[c + 1];
        }
    }
    el[node] = sl;
    er[node] = sr;
}

// ---------------------------------------------------------------------------
// fused softmax+gather (r6): back to the VERIFIED r4 shape (16 lanes per
// (node,head), 4 nodes/wave, head-slice == XCD, FETCH=33MB) with two
// per-edge instruction cuts. r5 post-mortem: 1-node/wave shape charged
// ~90 fixed instrs to ~16 edges (5.6/edge-head vs r4 2.5) -> 2.5x VALU
// time. Amortization rule: fixed cost per (node,head) must be <<16 edges.
//
// r6 cuts inside the r4 loop (VALU-bound per r4 counters):
//  1) (s*16, alpha) staged to padded LDS once per 16-edge chunk
//     (1 ds_write_b64); inner reads 2 pairs per ds_read_b128 broadcast
//     (0.5 instr/edge, replaces 2 ds_bpermute = 2 instr/edge).
//     Pad: group stride 18 pairs (144B) -> 4 groups on distinct banks.
//  2) u32 index math (stage s*16; inner addr = pq + lane, 1 v_add) ->
//     saddr-form loads, cutting the 64-bit addr chain.
// ---------------------------------------------------------------------------
__global__ __launch_bounds__(256) void k_gather8(const int* __restrict__ rowptr,
                                                 const int* __restrict__ csr_src,
                                                 const float* __restrict__ elT,
                                                 const float* __restrict__ erT,
                                                 const u32* __restrict__ featT2,
                                                 const float* __restrict__ bias,
                                                 u32* __restrict__ xout2) {
    __shared__ u32v2 sbuf[4][4][18];     // [wave][group][16 pairs + 2 pad]
    const int t = threadIdx.x;
    const int wv = t >> 6;
    const int grp = (t >> 4) & 3;
    const int h = blockIdx.x & 7;        // head slice == XCD (round-robin)
    const int d = (blockIdx.x >> 3) * 16 + (t >> 4);  // 3125*16 = 50000 exact
    const int lane = t & 15;
    const int b = rowptr[d], e = rowptr[d + 1];
    const float* __restrict__ elh = elT + (size_t)h * NN;
    const u32* __restrict__ fT = featT2 + (size_t)h * NN * 16;
    const float erd = erT[(size_t)h * NN + d];
    u32v2* __restrict__ sb = &sbuf[wv][grp][0];

    float a0 = 0.f, a1 = 0.f, ssum = 0.f;

    for (int c = b; c < e; c += 16) {
        const int idx = c + lane;
        // clamp keeps the load valid & line-hot; alpha forced to 0 on tail
        const int s_own = __builtin_nontemporal_load(csr_src + (idx < e ? idx : e - 1));
        const float ex_own = (idx < e) ? lexp(elh[(u32)s_own] + erd) : 0.f;
        ssum += ex_own;
        u32v2 pr;
        pr.x = (u32)s_own * 16u;
        pr.y = __float_as_uint(ex_own);
        sb[lane] = pr;
        __builtin_amdgcn_sched_barrier(0);
        const int nv = (e - c) < 16 ? (e - c) : 16;
        for (int i = 0; i < nv; i += 2) {
            const u32v4 pq = *(const u32v4*)&sb[i];   // 2 pairs, 16-lane bcast
            const float ai0 = __uint_as_float(pq.y);
            const u32 w0 = fT[pq.x + (u32)lane];
            a0 += bflo(w0) * ai0;
            a1 += bfhi(w0) * ai0;
            if (i + 1 < nv) {
                const float ai1 = __uint_as_float(pq.w);
                const u32 w1 = fT[pq.z + (u32)lane];
                a0 += bflo(w1) * ai1;
                a1 += bfhi(w1) * ai1;
            }
        }
        __builtin_amdgcn_sched_barrier(0);
    }

    // denominator: reduce across the 16-lane group (xor stays in-group)
    ssum += __shfl_xor(ssum, 1);
    ssum += __shfl_xor(ssum, 2);
    ssum += __shfl_xor(ssum, 4);
    ssum += __shfl_xor(ssum, 8);

    const float rd = 1.f / (ssum + 1e-9f);
    const f32x2 bb = *(const f32x2*)&bias[h * 32 + lane * 2];
    float v0 = a0 * rd + bb[0];
    float v1 = a1 * rd + bb[1];
    v0 = v0 > 0.f ? v0 : expm1f(v0);
    v1 = v1 > 0.f ? v1 : expm1f(v1);
    const u32 o = (u32)f2bf(v0) | ((u32)f2bf(v1) << 16);
    __builtin_nontemporal_store(o, xout2 + ((size_t)d * 128 + h * 16 + lane));
}

// layer-2 fused gather: 16 lanes/node x u32 (2 cols/lane), 4 nodes/wave.
__global__ __launch_bounds__(256) void k_gather1(const int* __restrict__ rowptr,
                                                 const int* __restrict__ csr_src,
                                                 const float* __restrict__ el,
                                                 const float* __restrict__ er,
                                                 const u32* __restrict__ featb2,
                                                 const float* __restrict__ bias,
                                                 void* __restrict__ out,
                                                 const int* __restrict__ flag, int n) {
    int t = threadIdx.x;
    int d = blockIdx.x * 16 + (t >> 4);
    int q = t & 15;           // owns cols 2q, 2q+1
    if (d >= n) return;
    int b = rowptr[d], e = rowptr[d + 1];
    float erd = er[d];
    float a0 = 0.f, a1 = 0.f, ssum = 0.f;
    int p = b;
    for (; p + 4 <= e; p += 4) {
        int s0 = csr_src[p], s1 = csr_src[p + 1], s2 = csr_src[p + 2], s3 = csr_src[p + 3];
        float e0 = lexp(el[s0] + erd);
        float e1 = lexp(el[s1] + erd);
        float e2 = lexp(el[s2] + erd);
        float e3 = lexp(el[s3] + erd);
        u32 w0 = featb2[(size_t)s0 * 16 + q];
        u32 w1 = featb2[(size_t)s1 * 16 + q];
        u32 w2 = featb2[(size_t)s2 * 16 + q];
        u32 w3 = featb2[(size_t)s3 * 16 + q];
        a0 += bflo(w0) * e0; a1 += bfhi(w0) * e0;
        a0 += bflo(w1) * e1; a1 += bfhi(w1) * e1;
        a0 += bflo(w2) * e2; a1 += bfhi(w2) * e2;
        a0 += bflo(w3) * e3; a1 += bfhi(w3) * e3;
        ssum += (e0 + e1) + (e2 + e3);
    }
    for (; p < e; ++p) {
        int s = csr_src[p];
        float ev = lexp(el[s] + erd);
        u32 w = featb2[(size_t)s * 16 + q];
        a0 += bflo(w) * ev;
        a1 += bfhi(w) * ev;
        ssum += ev;
    }
    float rd = 1.f / (ssum + 1e-9f);
    float v0 = a0 * rd + bias[2 * q];
    float v1 = a1 * rd + bias[2 * q + 1];
    if (*flag == 1) {
        f32x2 o = {v0, v1};
        ((f32x2*)out)[(size_t)d * 16 + q] = o;
    } else {
        ((u32*)out)[(size_t)d * 16 + q] = (u32)f2bf(v0) | ((u32)f2bf(v1) << 16);
    }
}

extern "C" void kernel_launch(void* const* d_in, const int* in_sizes, int n_in,
                              void* d_out, int out_size, void* d_ws, size_t ws_size,
                              hipStream_t stream) {
    const void* features = d_in[0];
    const int* src = (const int*)d_in[1];
    const int* dst = (const int*)d_in[2];

    char* ws = (char*)d_ws;
    size_t off = 0;
    auto carve = [&](size_t bytes) -> void* {
        void* p = ws + off;
        off = (off + bytes + 255) & ~(size_t)255;
        return p;
    };
    int*   flags = (int*)carve(64);
    float* pconv = (float*)carve(2048 * 4);
    u16*   Wp0 = (u16*)carve(65536 * 2);
    u16*   Wp1 = (u16*)carve(65536 * 2);
    u16*   Wp2 = (u16*)carve(8192 * 2);
    u16*   Xb    = (u16*)carve((size_t)NN * 256 * 2);  // bf16 hidden state (node-major)
    u16*   featb = (u16*)carve((size_t)NN * 256 * 2);  // bf16 GEMM output (head-major)
    float* el   = (float*)carve((size_t)NN * 8 * 4);
    float* er   = (float*)carve((size_t)NN * 8 * 4);
    int*   deg     = (int*)carve((size_t)NN * 4);
    int*   cursor  = (int*)carve((size_t)NN * 4);
    int*   rowptr  = (int*)carve((size_t)(NN + 1) * 4);
    int*   bsum    = (int*)carve(256 * 4);
    int*   csr_src = (int*)carve((size_t)NE * 4);
    if (off > ws_size) return;  // clean ws-too-small signature

    const int N = NN, E = NE;
    const int nscan = (N + 255) / 256;   // 196 <= 256

    DetectArgs da;
    const int din_idx[13] = {0, 3, 4, 5, 6, 7, 8, 9, 10, 11, 12, 13, 14};
    for (int j = 0; j < 13; ++j) {
        da.p[j] = (const u32*)d_in[din_idx[j]];
        int nw = in_sizes[din_idx[j]] / 2;
        da.nw[j] = nw > 512 ? 512 : nw;
    }
    k_detect<<<13, 256, 0, stream>>>(da, flags);

    // 9 small params -> fp32
    ConvArgs ca;
    const int psl[9] = {4, 5, 6, 8, 9, 10, 12, 13, 14};
    const int pfl[9] = {2, 3, 4, 6, 7, 8, 10, 11, 12};
    float* dsts[9];
    {
        size_t o = 0;
        for (int j = 0; j < 9; ++j) {
            dsts[j] = pconv + o;
            o += (size_t)in_sizes[psl[j]];
        }
    }
    for (int j = 0; j < 9; ++j) {
        ca.s[j] = d_in[psl[j]];
        ca.d[j] = dsts[j];
        ca.n[j] = in_sizes[psl[j]];
        ca.fi[j] = pfl[j];
    }
    k_convert<<<dim3(1, 9), 256, 0, stream>>>(ca, flags);
    float* al0f = dsts[0]; float* ar0f = dsts[1]; float* b0f = dsts[2];
    float* al1f = dsts[3]; float* ar1f = dsts[4]; float* b1f = dsts[5];
    float* al2f = dsts[6]; float* ar2f = dsts[7]; float* b2f = dsts[8];

    // W packing into B-frag order (once)
    k_wpack<<<32, 256, 0, stream>>>(d_in[3],  flags, 1, 256, Wp0, 8192);
    k_wpack<<<32, 256, 0, stream>>>(d_in[7],  flags, 5, 256, Wp1, 8192);
    k_wpack<<<4,  256, 0, stream>>>(d_in[11], flags, 9, 32,  Wp2, 1024);

    // CSR build (multi-block scan)
    hipMemsetAsync(deg, 0, (size_t)N * 4, stream);
    k_hist<<<(E + 255) / 256, 256, 0, stream>>>(dst, deg, E);
    k_scan_partial<<<nscan, 256, 0, stream>>>(deg, bsum, N);
    k_scan_bsum<<<1, 256, 0, stream>>>(bsum, nscan);
    k_scan_final<<<nscan, 256, 0, stream>>>(deg, bsum, rowptr, cursor, N);
    k_scatter<<<(E + 255) / 256, 256, 0, stream>>>(src, dst, cursor, csr_src, E);

    const dim3 ggrid((N + 63) / 64, 2);
    const dim3 egrid(nscan, 8);          // elr8: nodes x heads
    const int ggrid8 = 8 * (N / 16);     // 8 head-slices x 3125 node-groups

    // ---------------- layer 0 (reads features directly, dtype via flag) ----
    k_gemm_mfma<<<ggrid, 256, 0, stream>>>(features, flags, Wp0, featb, N);
    k_elr8<<<egrid, 256, 0, stream>>>(featb, al0f, ar0f, el, er, N);
    k_gather8<<<ggrid8, 256, 0, stream>>>(rowptr, csr_src, el, er,
                                          (const u32*)featb, b0f, (u32*)Xb);

    // ---------------- layer 1 ----------------
    k_gemm_mfma<<<ggrid, 256, 0, stream>>>(Xb, nullptr, Wp1, featb, N);
    k_elr8<<<egrid, 256, 0, stream>>>(featb, al1f, ar1f, el, er, N);
    k_gather8<<<ggrid8, 256, 0, stream>>>(rowptr, csr_src, el, er,
                                          (const u32*)featb, b1f, (u32*)Xb);

    // ---------------- layer 2 (1 head, D=32) ----------------
    k_gemm_mfma32<<<(N + 127) / 128, 256, 0, stream>>>(Xb, Wp2, featb, N);
    k_elr1<<<(N + 255) / 256, 256, 0, stream>>>(featb, al2f, ar2f, el, er, N);
    k_gather1<<<(N + 15) / 16, 256, 0, stream>>>(rowptr, csr_src, el, er,
                                                 (const u32*)featb, b2f,
                                                 d_out, flags, N);
}

// Round 7
// 492.559 us; speedup vs baseline: 1.3436x; 1.1132x over previous
//
#include <hip/hip_runtime.h>

typedef unsigned short u16;
typedef unsigned int   u32;
typedef __attribute__((ext_vector_type(8))) short  short8;
typedef __attribute__((ext_vector_type(4))) float  f32x4;
typedef __attribute__((ext_vector_type(2))) float  f32x2;
typedef __attribute__((ext_vector_type(2))) unsigned int u32v2;
typedef __attribute__((ext_vector_type(4))) unsigned int u32v4;

#define NN 50000
#define NE 800000

__device__ __forceinline__ float bf2f(u16 b) { return __uint_as_float(((u32)b) << 16); }
__device__ __forceinline__ float bflo(u32 p) { return __uint_as_float(p << 16); }
__device__ __forceinline__ float bfhi(u32 p) { return __uint_as_float(p & 0xffff0000u); }
__device__ __forceinline__ u16 f2bf(float f) {
    u32 u = __float_as_uint(f);
    u32 r = u + 0x7fffu + ((u >> 16) & 1u);
    return (u16)(r >> 16);
}
// leaky-relu + clamped exp (clamp is identity for this data's logit range)
__device__ __forceinline__ float lexp(float v) {
    v = fmaxf(v, 0.2f * v);
    return __expf(fminf(v, 60.f));
}

// ---------------------------------------------------------------------------
// dtype detection (parallel): flag 0=bf16, 1=fp32, 2=all-zero
// ---------------------------------------------------------------------------
struct DetectArgs { const u32* p[13]; int nw[13]; };

__global__ __launch_bounds__(256) void k_detect(DetectArgs a, int* flags) {
    __shared__ int sh[256], sz[256];
    int j = blockIdx.x;
    const u32* x = a.p[j];
    int n = a.nw[j];
    int t = threadIdx.x;
    int hits = 0, nz = 0;
    for (int i = t; i < n; i += 256) {
        u32 w = x[i];
        if (w) {
            ++nz;
            u32 e = (w >> 7) & 0xffu;
            if (e >= 100 && e <= 150) ++hits;
        }
    }
    sh[t] = hits; sz[t] = nz;
    __syncthreads();
    for (int ofs = 128; ofs > 0; ofs >>= 1) {
        if (t < ofs) { sh[t] += sh[t + ofs]; sz[t] += sz[t + ofs]; }
        __syncthreads();
    }
    if (t == 0) flags[j] = (sz[0] == 0) ? 2 : ((sh[0] * 2 >= sz[0]) ? 0 : 1);
}

// convert ONLY the 9 small attention params (al/ar/b x 3 layers) to fp32.
struct ConvArgs { const void* s[9]; float* d[9]; int n[9]; int fi[9]; };

__global__ void k_convert(ConvArgs a, const int* __restrict__ flags) {
    int j = blockIdx.y;
    int i = blockIdx.x * 256 + threadIdx.x;
    if (i >= a.n[j]) return;
    int fl = flags[a.fi[j]];
    float v = 0.f;
    if (fl == 1) v = ((const float*)a.s[j])[i];
    else if (fl == 0) v = bf2f(((const u16*)a.s[j])[i]);
    a.d[j][i] = v;
}

// pack W[K=256][N] into MFMA B-fragment order:
// chunk id = (nt*8 + kt)*64 + L holds 8 bf16: W[kt*32 + (L>>4)*8 + j][nt*16 + (L&15)]
__global__ void k_wpack(const void* __restrict__ Wsrc, const int* __restrict__ flags,
                        int fidx, int N, u16* __restrict__ Wp, int nchunks) {
    int id = blockIdx.x * 256 + threadIdx.x;
    if (id >= nchunks) return;
    int L = id & 63, kt = (id >> 6) & 7, nt = id >> 9;
    int col = nt * 16 + (L & 15);
    int krow = kt * 32 + ((L >> 4) & 3) * 8;
    bool isf32 = (flags[fidx] == 1);
#pragma unroll
    for (int j = 0; j < 8; ++j) {
        int s = (krow + j) * N + col;
        Wp[id * 8 + j] = isf32 ? f2bf(((const float*)Wsrc)[s]) : ((const u16*)Wsrc)[s];
    }
}

// ---------------------------------------------------------------------------
// CSR build (graph static across layers) — 3-phase multi-block scan
// ---------------------------------------------------------------------------
__global__ void k_hist(const int* __restrict__ dst, int* __restrict__ deg, int E) {
    int e = blockIdx.x * 256 + threadIdx.x;
    if (e < E) atomicAdd(&deg[dst[e]], 1);
}

__global__ __launch_bounds__(256) void k_scan_partial(const int* __restrict__ deg,
                                                      int* __restrict__ bsum, int n) {
    __shared__ int red[256];
    int t = threadIdx.x;
    int i = blockIdx.x * 256 + t;
    red[t] = (i < n) ? deg[i] : 0;
    __syncthreads();
    for (int ofs = 128; ofs > 0; ofs >>= 1) {
        if (t < ofs) red[t] += red[t + ofs];
        __syncthreads();
    }
    if (t == 0) bsum[blockIdx.x] = red[0];
}

__global__ __launch_bounds__(256) void k_scan_bsum(int* __restrict__ bsum, int nb) {
    __shared__ int s[256];
    int t = threadIdx.x;
    int v = (t < nb) ? bsum[t] : 0;
    s[t] = v;
    __syncthreads();
    for (int ofs = 1; ofs < 256; ofs <<= 1) {
        int x = (t >= ofs) ? s[t - ofs] : 0;
        __syncthreads();
        s[t] += x;
        __syncthreads();
    }
    if (t < nb) bsum[t] = s[t] - v;   // exclusive
}

__global__ __launch_bounds__(256) void k_scan_final(const int* __restrict__ deg,
                                                    const int* __restrict__ bsum,
                                                    int* __restrict__ rowptr,
                                                    int* __restrict__ cursor, int n) {
    __shared__ int s[256];
    int t = threadIdx.x;
    int i = blockIdx.x * 256 + t;
    int v = (i < n) ? deg[i] : 0;
    s[t] = v;
    __syncthreads();
    for (int ofs = 1; ofs < 256; ofs <<= 1) {
        int x = (t >= ofs) ? s[t - ofs] : 0;
        __syncthreads();
        s[t] += x;
        __syncthreads();
    }
    int excl = bsum[blockIdx.x] + s[t] - v;
    if (i < n) {
        rowptr[i] = excl;
        cursor[i] = excl;
        if (i == n - 1) rowptr[n] = excl + v;
    }
}

__global__ void k_scatter(const int* __restrict__ src, const int* __restrict__ dst,
                          int* __restrict__ cursor, int* __restrict__ csr_src, int E) {
    int e = blockIdx.x * 256 + threadIdx.x;
    if (e >= E) return;
    int p = atomicAdd(&cursor[dst[e]], 1);
    csr_src[p] = src[e];
}

// ---------------------------------------------------------------------------
// MFMA GEMM: [nrows,256] x Wp(packed bf16) -> bf16 featT (HEAD-MAJOR:
// featT[h][row][32]) so each head slice is a contiguous 3.2MB block ->
// one XCD's L2 holds its slice (r4: FETCH 338->33MB, verified).
// As staging XOR-swizzled (bank-conflict fix, r2).
// ---------------------------------------------------------------------------
__global__ __launch_bounds__(256) void k_gemm_mfma(const void* __restrict__ Xv,
                                                   const int* __restrict__ xflag,
                                                   const u16* __restrict__ Wp,
                                                   u16* __restrict__ OUT, int nrows) {
    __shared__ u16 As[64 * 256];   // 32 KB
    const int t = threadIdx.x;
    const int w = t >> 6, L = t & 63;
    const int quad = (L >> 4) & 3;
    const int r0 = blockIdx.x * 64;
    const int nb = blockIdx.y * 8;
    const bool xf32 = (xflag != nullptr) && (*xflag == 1);

    short8* Asv = (short8*)As;
    short8 zero = {0, 0, 0, 0, 0, 0, 0, 0};
#pragma unroll
    for (int i = 0; i < 8; ++i) {
        int g = i * 256 + t;
        int row = g >> 5, cc = g & 31;
        int r = r0 + row;
        short8 val = zero;
        if (r < nrows) {
            if (xf32) {
                const f32x4* Xf4 = (const f32x4*)Xv;
                f32x4 lo = Xf4[(size_t)r * 64 + cc * 2];
                f32x4 hi = Xf4[(size_t)r * 64 + cc * 2 + 1];
                val[0] = (short)f2bf(lo[0]); val[1] = (short)f2bf(lo[1]);
                val[2] = (short)f2bf(lo[2]); val[3] = (short)f2bf(lo[3]);
                val[4] = (short)f2bf(hi[0]); val[5] = (short)f2bf(hi[1]);
                val[6] = (short)f2bf(hi[2]); val[7] = (short)f2bf(hi[3]);
            } else {
                val = ((const short8*)Xv)[(size_t)r * 32 + cc];
            }
        }
        Asv[cc * 64 + (row ^ (cc & 7))] = val;
    }

    const short8* Wv = (const short8*)Wp;
    short8 bf[2][8];
#pragma unroll
    for (int jn = 0; jn < 2; ++jn) {
        int nt = nb + w + jn * 4;
#pragma unroll
        for (int kt = 0; kt < 8; ++kt) bf[jn][kt] = Wv[(nt * 8 + kt) * 64 + L];
    }
    __syncthreads();

    f32x4 acc[4][2];
#pragma unroll
    for (int mi = 0; mi < 4; ++mi)
#pragma unroll
        for (int jn = 0; jn < 2; ++jn) acc[mi][jn] = (f32x4){0.f, 0.f, 0.f, 0.f};

#pragma unroll
    for (int kt = 0; kt < 8; ++kt) {
        const int ccr = kt * 4 + quad;
#pragma unroll
        for (int mi = 0; mi < 4; ++mi) {
            short8 af = Asv[ccr * 64 + ((mi * 16 + (L & 15)) ^ (ccr & 7))];
            acc[mi][0] = __builtin_amdgcn_mfma_f32_16x16x32_bf16(af, bf[0][kt], acc[mi][0], 0, 0, 0);
            acc[mi][1] = __builtin_amdgcn_mfma_f32_16x16x32_bf16(af, bf[1][kt], acc[mi][1], 0, 0, 0);
        }
    }

    const int colbase = blockIdx.y * 128;
#pragma unroll
    for (int mi = 0; mi < 4; ++mi) {
        int rb = r0 + mi * 16 + quad * 4;
#pragma unroll
        for (int jn = 0; jn < 2; ++jn) {
            int c = colbase + (w + jn * 4) * 16 + (L & 15);
            const size_t hb = (size_t)(c >> 5) * nrows * 32 + (c & 31);
#pragma unroll
            for (int reg = 0; reg < 4; ++reg) {
                int r = rb + reg;
                if (r < nrows) OUT[hb + (size_t)r * 32] = f2bf(acc[mi][jn][reg]);
            }
        }
    }
}

// MFMA GEMM layer 2: [nrows,256](bf16) x Wp2 -> bf16 [nrows,32] (node-major;
// single head, no slicing downstream). BM=128, BN=32.
__global__ __launch_bounds__(256) void k_gemm_mfma32(const u16* __restrict__ Xb,
                                                     const u16* __restrict__ Wp,
                                                     u16* __restrict__ OUT, int nrows) {
    __shared__ u16 As[128 * 256];  // 64 KB
    const int t = threadIdx.x;
    const int w = t >> 6, L = t & 63;
    const int quad = (L >> 4) & 3;
    const int r0 = blockIdx.x * 128;
    const int mh = (w >> 1) * 64, nt = w & 1;

    const short8* Xv = (const short8*)Xb;
    short8* Asv = (short8*)As;
    short8 zero = {0, 0, 0, 0, 0, 0, 0, 0};
#pragma unroll
    for (int i = 0; i < 16; ++i) {
        int g = i * 256 + t;
        int row = g >> 5, cc = g & 31;
        int r = r0 + row;
        Asv[cc * 128 + (row ^ (cc & 7))] = (r < nrows) ? Xv[(size_t)r * 32 + cc] : zero;
    }

    const short8* Wv = (const short8*)Wp;
    short8 bf[8];
#pragma unroll
    for (int kt = 0; kt < 8; ++kt) bf[kt] = Wv[(nt * 8 + kt) * 64 + L];
    __syncthreads();

    f32x4 acc[4];
#pragma unroll
    for (int mi = 0; mi < 4; ++mi) acc[mi] = (f32x4){0.f, 0.f, 0.f, 0.f};

#pragma unroll
    for (int kt = 0; kt < 8; ++kt) {
        const int ccr = kt * 4 + quad;
#pragma unroll
        for (int mi = 0; mi < 4; ++mi) {
            short8 af = Asv[ccr * 128 + ((mh + mi * 16 + (L & 15)) ^ (ccr & 7))];
            acc[mi] = __builtin_amdgcn_mfma_f32_16x16x32_bf16(af, bf[kt], acc[mi], 0, 0, 0);
        }
    }

#pragma unroll
    for (int mi = 0; mi < 4; ++mi) {
        int rb = r0 + mh + mi * 16 + quad * 4;
        int c = nt * 16 + (L & 15);
#pragma unroll
        for (int reg = 0; reg < 4; ++reg) {
            int r = rb + reg;
            if (r < nrows) OUT[(size_t)r * 32 + c] = f2bf(acc[mi][reg]);
        }
    }
}

// attention logit dots, head-major feat: featT[h][node][32 bf16].
// writes elT/erT [8][N] (head-major, 200KB/slice -> L2-resident in gather)
__global__ void k_elr8(const u16* __restrict__ featT, const float* __restrict__ al,
                       const float* __restrict__ ar, float* __restrict__ elT,
                       float* __restrict__ erT, int n) {
    int node = blockIdx.x * 256 + threadIdx.x;
    int h = blockIdx.y;
    if (node >= n) return;
    const u32v4* fu = (const u32v4*)((const u32*)featT + ((size_t)h * n + node) * 16);
    const float* A = al + h * 32;
    const float* B = ar + h * 32;
    float sl = 0.f, sr = 0.f;
#pragma unroll
    for (int j = 0; j < 4; ++j) {
        u32v4 w4 = fu[j];
#pragma unroll
        for (int k = 0; k < 4; ++k) {
            u32 w = (k == 0) ? w4.x : (k == 1) ? w4.y : (k == 2) ? w4.z : w4.w;
            float f0 = bflo(w), f1 = bfhi(w);
            int c = j * 8 + k * 2;
            sl += f0 * A[c] + f1 * A[c + 1];
            sr += f0 * B[c] + f1 * B[c + 1];
        }
    }
    elT[(size_t)h * n + node] = sl;
    erT[(size_t)h * n + node] = sr;
}

__global__ void k_elr1(const u16* __restrict__ featb, const float* __restrict__ al,
                       const float* __restrict__ ar, float* __restrict__ el,
                       float* __restrict__ er, int n) {
    int node = blockIdx.x * 256 + threadIdx.x;
    if (node >= n) return;
    const u32v4* fu = (const u32v4*)((const u32*)featb + (size_t)node * 16);
    float sl = 0.f, sr = 0.f;
#pragma unroll
    for (int j = 0; j < 4; ++j) {
        u32v4 w4 = fu[j];
#pragma unroll
        for (int k = 0; k < 4; ++k) {
            u32 w = (k == 0) ? w4.x : (k == 1) ? w4.y : (k == 2) ? w4.z : w4.w;
            float f0 = bflo(w), f1 = bfhi(w);
            int c = j * 8 + k * 2;
            sl += f0 * al[c] + f1 * al[c + 1];
            sr += f0 * ar[c] + f1 * ar[c + 1];
        }
    }
    el[node] = sl;
    er[node] = sr;
}

// ---------------------------------------------------------------------------
// fused softmax+gather (r7): r4 shape (16 lanes/(node,head), 4 nodes/wave,
// head-slice==XCD, FETCH 33MB verified) + r6's instruction cuts (LDS pair
// staging, u32 saddr addressing) + r4's ILP restored.
//
// r6 post-mortem: VALU instr cut confirmed (VALUBusy 69->38, VGPR 12) but
// dur 103->130: DYNAMIC trip count killed unrolling -> serial ds_read ->
// load -> FMA chain, ~1 load in flight (r4 had 16). Lesson: constant
// trip count (always 16 slots; tail alpha=0, clamped hot index) is what
// buys the MLP. Inner loop = 2 half-passes of {4x ds_read_b128 -> 8
// independent feat loads -> 16 FMA}; 8 loads in flight, VGPR < 64.
// ---------------------------------------------------------------------------
__global__ __launch_bounds__(256) void k_gather8(const int* __restrict__ rowptr,
                                                 const int* __restrict__ csr_src,
                                                 const float* __restrict__ elT,
                                                 const float* __restrict__ erT,
                                                 const u32* __restrict__ featT2,
                                                 const float* __restrict__ bias,
                                                 u32* __restrict__ xout2) {
    __shared__ u32v2 sbuf[4][4][18];     // [wave][group][16 pairs + 2 pad]
    const int t = threadIdx.x;
    const int wv = t >> 6;
    const int grp = (t >> 4) & 3;
    const int h = blockIdx.x & 7;        // head slice == XCD (round-robin)
    const int d = (blockIdx.x >> 3) * 16 + (t >> 4);  // 3125*16 = 50000 exact
    const int lane = t & 15;
    const int b = rowptr[d], e = rowptr[d + 1];
    const float* __restrict__ elh = elT + (size_t)h * NN;
    const u32* __restrict__ fT = featT2 + (size_t)h * NN * 16;
    const float erd = erT[(size_t)h * NN + d];
    u32v2* __restrict__ sb = &sbuf[wv][grp][0];

    float a0 = 0.f, a1 = 0.f, ssum = 0.f;

    for (int c = b; c < e; c += 16) {
        const int idx = c + lane;
        // clamp keeps the load valid & line-hot; alpha forced to 0 on tail
        const int s_own = __builtin_nontemporal_load(csr_src + (idx < e ? idx : e - 1));
        const float ex_own = (idx < e) ? lexp(elh[(u32)s_own] + erd) : 0.f;
        ssum += ex_own;
        u32v2 pr;
        pr.x = (u32)s_own * 16u;
        pr.y = __float_as_uint(ex_own);
        sb[lane] = pr;
        __builtin_amdgcn_sched_barrier(0);
        // constant 16 slots, two half-passes: 4 ds_read_b128 -> 8 loads -> FMA
#pragma unroll
        for (int half = 0; half < 2; ++half) {
            const u32v4 pq0 = *(const u32v4*)&sb[half * 8 + 0];
            const u32v4 pq1 = *(const u32v4*)&sb[half * 8 + 2];
            const u32v4 pq2 = *(const u32v4*)&sb[half * 8 + 4];
            const u32v4 pq3 = *(const u32v4*)&sb[half * 8 + 6];
            const u32 w0 = fT[pq0.x + (u32)lane];
            const u32 w1 = fT[pq0.z + (u32)lane];
            const u32 w2 = fT[pq1.x + (u32)lane];
            const u32 w3 = fT[pq1.z + (u32)lane];
            const u32 w4 = fT[pq2.x + (u32)lane];
            const u32 w5 = fT[pq2.z + (u32)lane];
            const u32 w6 = fT[pq3.x + (u32)lane];
            const u32 w7 = fT[pq3.z + (u32)lane];
            const float ai0 = __uint_as_float(pq0.y), ai1 = __uint_as_float(pq0.w);
            const float ai2 = __uint_as_float(pq1.y), ai3 = __uint_as_float(pq1.w);
            const float ai4 = __uint_as_float(pq2.y), ai5 = __uint_as_float(pq2.w);
            const float ai6 = __uint_as_float(pq3.y), ai7 = __uint_as_float(pq3.w);
            a0 += bflo(w0) * ai0; a1 += bfhi(w0) * ai0;
            a0 += bflo(w1) * ai1; a1 += bfhi(w1) * ai1;
            a0 += bflo(w2) * ai2; a1 += bfhi(w2) * ai2;
            a0 += bflo(w3) * ai3; a1 += bfhi(w3) * ai3;
            a0 += bflo(w4) * ai4; a1 += bfhi(w4) * ai4;
            a0 += bflo(w5) * ai5; a1 += bfhi(w5) * ai5;
            a0 += bflo(w6) * ai6; a1 += bfhi(w6) * ai6;
            a0 += bflo(w7) * ai7; a1 += bfhi(w7) * ai7;
        }
        __builtin_amdgcn_sched_barrier(0);
    }

    // denominator: reduce across the 16-lane group (xor stays in-group)
    ssum += __shfl_xor(ssum, 1);
    ssum += __shfl_xor(ssum, 2);
    ssum += __shfl_xor(ssum, 4);
    ssum += __shfl_xor(ssum, 8);

    const float rd = 1.f / (ssum + 1e-9f);
    const f32x2 bb = *(const f32x2*)&bias[h * 32 + lane * 2];
    float v0 = a0 * rd + bb[0];
    float v1 = a1 * rd + bb[1];
    v0 = v0 > 0.f ? v0 : expm1f(v0);
    v1 = v1 > 0.f ? v1 : expm1f(v1);
    const u32 o = (u32)f2bf(v0) | ((u32)f2bf(v1) << 16);
    __builtin_nontemporal_store(o, xout2 + ((size_t)d * 128 + h * 16 + lane));
}

// layer-2 fused gather: 16 lanes/node x u32 (2 cols/lane), 4 nodes/wave.
__global__ __launch_bounds__(256) void k_gather1(const int* __restrict__ rowptr,
                                                 const int* __restrict__ csr_src,
                                                 const float* __restrict__ el,
                                                 const float* __restrict__ er,
                                                 const u32* __restrict__ featb2,
                                                 const float* __restrict__ bias,
                                                 void* __restrict__ out,
                                                 const int* __restrict__ flag, int n) {
    int t = threadIdx.x;
    int d = blockIdx.x * 16 + (t >> 4);
    int q = t & 15;           // owns cols 2q, 2q+1
    if (d >= n) return;
    int b = rowptr[d], e = rowptr[d + 1];
    float erd = er[d];
    float a0 = 0.f, a1 = 0.f, ssum = 0.f;
    int p = b;
    for (; p + 4 <= e; p += 4) {
        int s0 = csr_src[p], s1 = csr_src[p + 1], s2 = csr_src[p + 2], s3 = csr_src[p + 3];
        float e0 = lexp(el[s0] + erd);
        float e1 = lexp(el[s1] + erd);
        float e2 = lexp(el[s2] + erd);
        float e3 = lexp(el[s3] + erd);
        u32 w0 = featb2[(size_t)s0 * 16 + q];
        u32 w1 = featb2[(size_t)s1 * 16 + q];
        u32 w2 = featb2[(size_t)s2 * 16 + q];
        u32 w3 = featb2[(size_t)s3 * 16 + q];
        a0 += bflo(w0) * e0; a1 += bfhi(w0) * e0;
        a0 += bflo(w1) * e1; a1 += bfhi(w1) * e1;
        a0 += bflo(w2) * e2; a1 += bfhi(w2) * e2;
        a0 += bflo(w3) * e3; a1 += bfhi(w3) * e3;
        ssum += (e0 + e1) + (e2 + e3);
    }
    for (; p < e; ++p) {
        int s = csr_src[p];
        float ev = lexp(el[s] + erd);
        u32 w = featb2[(size_t)s * 16 + q];
        a0 += bflo(w) * ev;
        a1 += bfhi(w) * ev;
        ssum += ev;
    }
    float rd = 1.f / (ssum + 1e-9f);
    float v0 = a0 * rd + bias[2 * q];
    float v1 = a1 * rd + bias[2 * q + 1];
    if (*flag == 1) {
        f32x2 o = {v0, v1};
        ((f32x2*)out)[(size_t)d * 16 + q] = o;
    } else {
        ((u32*)out)[(size_t)d * 16 + q] = (u32)f2bf(v0) | ((u32)f2bf(v1) << 16);
    }
}

extern "C" void kernel_launch(void* const* d_in, const int* in_sizes, int n_in,
                              void* d_out, int out_size, void* d_ws, size_t ws_size,
                              hipStream_t stream) {
    const void* features = d_in[0];
    const int* src = (const int*)d_in[1];
    const int* dst = (const int*)d_in[2];

    char* ws = (char*)d_ws;
    size_t off = 0;
    auto carve = [&](size_t bytes) -> void* {
        void* p = ws + off;
        off = (off + bytes + 255) & ~(size_t)255;
        return p;
    };
    int*   flags = (int*)carve(64);
    float* pconv = (float*)carve(2048 * 4);
    u16*   Wp0 = (u16*)carve(65536 * 2);
    u16*   Wp1 = (u16*)carve(65536 * 2);
    u16*   Wp2 = (u16*)carve(8192 * 2);
    u16*   Xb    = (u16*)carve((size_t)NN * 256 * 2);  // bf16 hidden state (node-major)
    u16*   featb = (u16*)carve((size_t)NN * 256 * 2);  // bf16 GEMM output (head-major)
    float* el   = (float*)carve((size_t)NN * 8 * 4);
    float* er   = (float*)carve((size_t)NN * 8 * 4);
    int*   deg     = (int*)carve((size_t)NN * 4);
    int*   cursor  = (int*)carve((size_t)NN * 4);
    int*   rowptr  = (int*)carve((size_t)(NN + 1) * 4);
    int*   bsum    = (int*)carve(256 * 4);
    int*   csr_src = (int*)carve((size_t)NE * 4);
    if (off > ws_size) return;  // clean ws-too-small signature

    const int N = NN, E = NE;
    const int nscan = (N + 255) / 256;   // 196 <= 256

    DetectArgs da;
    const int din_idx[13] = {0, 3, 4, 5, 6, 7, 8, 9, 10, 11, 12, 13, 14};
    for (int j = 0; j < 13; ++j) {
        da.p[j] = (const u32*)d_in[din_idx[j]];
        int nw = in_sizes[din_idx[j]] / 2;
        da.nw[j] = nw > 512 ? 512 : nw;
    }
    k_detect<<<13, 256, 0, stream>>>(da, flags);

    // 9 small params -> fp32
    ConvArgs ca;
    const int psl[9] = {4, 5, 6, 8, 9, 10, 12, 13, 14};
    const int pfl[9] = {2, 3, 4, 6, 7, 8, 10, 11, 12};
    float* dsts[9];
    {
        size_t o = 0;
        for (int j = 0; j < 9; ++j) {
            dsts[j] = pconv + o;
            o += (size_t)in_sizes[psl[j]];
        }
    }
    for (int j = 0; j < 9; ++j) {
        ca.s[j] = d_in[psl[j]];
        ca.d[j] = dsts[j];
        ca.n[j] = in_sizes[psl[j]];
        ca.fi[j] = pfl[j];
    }
    k_convert<<<dim3(1, 9), 256, 0, stream>>>(ca, flags);
    float* al0f = dsts[0]; float* ar0f = dsts[1]; float* b0f = dsts[2];
    float* al1f = dsts[3]; float* ar1f = dsts[4]; float* b1f = dsts[5];
    float* al2f = dsts[6]; float* ar2f = dsts[7]; float* b2f = dsts[8];

    // W packing into B-frag order (once)
    k_wpack<<<32, 256, 0, stream>>>(d_in[3],  flags, 1, 256, Wp0, 8192);
    k_wpack<<<32, 256, 0, stream>>>(d_in[7],  flags, 5, 256, Wp1, 8192);
    k_wpack<<<4,  256, 0, stream>>>(d_in[11], flags, 9, 32,  Wp2, 1024);

    // CSR build (multi-block scan)
    hipMemsetAsync(deg, 0, (size_t)N * 4, stream);
    k_hist<<<(E + 255) / 256, 256, 0, stream>>>(dst, deg, E);
    k_scan_partial<<<nscan, 256, 0, stream>>>(deg, bsum, N);
    k_scan_bsum<<<1, 256, 0, stream>>>(bsum, nscan);
    k_scan_final<<<nscan, 256, 0, stream>>>(deg, bsum, rowptr, cursor, N);
    k_scatter<<<(E + 255) / 256, 256, 0, stream>>>(src, dst, cursor, csr_src, E);

    const dim3 ggrid((N + 63) / 64, 2);
    const dim3 egrid(nscan, 8);          // elr8: nodes x heads
    const int ggrid8 = 8 * (N / 16);     // 8 head-slices x 3125 node-groups

    // ---------------- layer 0 (reads features directly, dtype via flag) ----
    k_gemm_mfma<<<ggrid, 256, 0, stream>>>(features, flags, Wp0, featb, N);
    k_elr8<<<egrid, 256, 0, stream>>>(featb, al0f, ar0f, el, er, N);
    k_gather8<<<ggrid8, 256, 0, stream>>>(rowptr, csr_src, el, er,
                                          (const u32*)featb, b0f, (u32*)Xb);

    // ---------------- layer 1 ----------------
    k_gemm_mfma<<<ggrid, 256, 0, stream>>>(Xb, nullptr, Wp1, featb, N);
    k_elr8<<<egrid, 256, 0, stream>>>(featb, al1f, ar1f, el, er, N);
    k_gather8<<<ggrid8, 256, 0, stream>>>(rowptr, csr_src, el, er,
                                          (const u32*)featb, b1f, (u32*)Xb);

    // ---------------- layer 2 (1 head, D=32) ----------------
    k_gemm_mfma32<<<(N + 127) / 128, 256, 0, stream>>>(Xb, Wp2, featb, N);
    k_elr1<<<(N + 255) / 256, 256, 0, stream>>>(featb, al2f, ar2f, el, er, N);
    k_gather1<<<(N + 15) / 16, 256, 0, stream>>>(rowptr, csr_src, el, er,
                                                 (const u32*)featb, b2f,
                                                 d_out, flags, N);
}

// Round 8
// 447.323 us; speedup vs baseline: 1.4795x; 1.1011x over previous
//
#include <hip/hip_runtime.h>

typedef unsigned short u16;
typedef unsigned int   u32;
typedef __attribute__((ext_vector_type(8))) short  short8;
typedef __attribute__((ext_vector_type(4))) float  f32x4;
typedef __attribute__((ext_vector_type(2))) float  f32x2;
typedef __attribute__((ext_vector_type(2))) unsigned int u32v2;
typedef __attribute__((ext_vector_type(4))) unsigned int u32v4;

#define NN 50000
#define NE 800000

__device__ __forceinline__ float bf2f(u16 b) { return __uint_as_float(((u32)b) << 16); }
__device__ __forceinline__ float bflo(u32 p) { return __uint_as_float(p << 16); }
__device__ __forceinline__ float bfhi(u32 p) { return __uint_as_float(p & 0xffff0000u); }
__device__ __forceinline__ u16 f2bf(float f) {
    u32 u = __float_as_uint(f);
    u32 r = u + 0x7fffu + ((u >> 16) & 1u);
    return (u16)(r >> 16);
}
// leaky-relu + clamped exp (clamp is identity for this data's logit range)
__device__ __forceinline__ float lexp(float v) {
    v = fmaxf(v, 0.2f * v);
    return __expf(fminf(v, 60.f));
}

// ---------------------------------------------------------------------------
// dtype detection (parallel): flag 0=bf16, 1=fp32, 2=all-zero
// ---------------------------------------------------------------------------
struct DetectArgs { const u32* p[13]; int nw[13]; };

__global__ __launch_bounds__(256) void k_detect(DetectArgs a, int* flags) {
    __shared__ int sh[256], sz[256];
    int j = blockIdx.x;
    const u32* x = a.p[j];
    int n = a.nw[j];
    int t = threadIdx.x;
    int hits = 0, nz = 0;
    for (int i = t; i < n; i += 256) {
        u32 w = x[i];
        if (w) {
            ++nz;
            u32 e = (w >> 7) & 0xffu;
            if (e >= 100 && e <= 150) ++hits;
        }
    }
    sh[t] = hits; sz[t] = nz;
    __syncthreads();
    for (int ofs = 128; ofs > 0; ofs >>= 1) {
        if (t < ofs) { sh[t] += sh[t + ofs]; sz[t] += sz[t + ofs]; }
        __syncthreads();
    }
    if (t == 0) flags[j] = (sz[0] == 0) ? 2 : ((sh[0] * 2 >= sz[0]) ? 0 : 1);
}

// convert ONLY the 9 small attention params (al/ar/b x 3 layers) to fp32.
struct ConvArgs { const void* s[9]; float* d[9]; int n[9]; int fi[9]; };

__global__ void k_convert(ConvArgs a, const int* __restrict__ flags) {
    int j = blockIdx.y;
    int i = blockIdx.x * 256 + threadIdx.x;
    if (i >= a.n[j]) return;
    int fl = flags[a.fi[j]];
    float v = 0.f;
    if (fl == 1) v = ((const float*)a.s[j])[i];
    else if (fl == 0) v = bf2f(((const u16*)a.s[j])[i]);
    a.d[j][i] = v;
}

// pack W[K=256][N] into MFMA B-fragment order:
// chunk id = (nt*8 + kt)*64 + L holds 8 bf16: W[kt*32 + (L>>4)*8 + j][nt*16 + (L&15)]
__global__ void k_wpack(const void* __restrict__ Wsrc, const int* __restrict__ flags,
                        int fidx, int N, u16* __restrict__ Wp, int nchunks) {
    int id = blockIdx.x * 256 + threadIdx.x;
    if (id >= nchunks) return;
    int L = id & 63, kt = (id >> 6) & 7, nt = id >> 9;
    int col = nt * 16 + (L & 15);
    int krow = kt * 32 + ((L >> 4) & 3) * 8;
    bool isf32 = (flags[fidx] == 1);
#pragma unroll
    for (int j = 0; j < 8; ++j) {
        int s = (krow + j) * N + col;
        Wp[id * 8 + j] = isf32 ? f2bf(((const float*)Wsrc)[s]) : ((const u16*)Wsrc)[s];
    }
}

// ---------------------------------------------------------------------------
// CSR build (graph static across layers) — 3-phase multi-block scan
// ---------------------------------------------------------------------------
__global__ void k_hist(const int* __restrict__ dst, int* __restrict__ deg, int E) {
    int e = blockIdx.x * 256 + threadIdx.x;
    if (e < E) atomicAdd(&deg[dst[e]], 1);
}

__global__ __launch_bounds__(256) void k_scan_partial(const int* __restrict__ deg,
                                                      int* __restrict__ bsum, int n) {
    __shared__ int red[256];
    int t = threadIdx.x;
    int i = blockIdx.x * 256 + t;
    red[t] = (i < n) ? deg[i] : 0;
    __syncthreads();
    for (int ofs = 128; ofs > 0; ofs >>= 1) {
        if (t < ofs) red[t] += red[t + ofs];
        __syncthreads();
    }
    if (t == 0) bsum[blockIdx.x] = red[0];
}

__global__ __launch_bounds__(256) void k_scan_bsum(int* __restrict__ bsum, int nb) {
    __shared__ int s[256];
    int t = threadIdx.x;
    int v = (t < nb) ? bsum[t] : 0;
    s[t] = v;
    __syncthreads();
    for (int ofs = 1; ofs < 256; ofs <<= 1) {
        int x = (t >= ofs) ? s[t - ofs] : 0;
        __syncthreads();
        s[t] += x;
        __syncthreads();
    }
    if (t < nb) bsum[t] = s[t] - v;   // exclusive
}

__global__ __launch_bounds__(256) void k_scan_final(const int* __restrict__ deg,
                                                    const int* __restrict__ bsum,
                                                    int* __restrict__ rowptr,
                                                    int* __restrict__ cursor, int n) {
    __shared__ int s[256];
    int t = threadIdx.x;
    int i = blockIdx.x * 256 + t;
    int v = (i < n) ? deg[i] : 0;
    s[t] = v;
    __syncthreads();
    for (int ofs = 1; ofs < 256; ofs <<= 1) {
        int x = (t >= ofs) ? s[t - ofs] : 0;
        __syncthreads();
        s[t] += x;
        __syncthreads();
    }
    int excl = bsum[blockIdx.x] + s[t] - v;
    if (i < n) {
        rowptr[i] = excl;
        cursor[i] = excl;
        if (i == n - 1) rowptr[n] = excl + v;
    }
}

__global__ void k_scatter(const int* __restrict__ src, const int* __restrict__ dst,
                          int* __restrict__ cursor, int* __restrict__ csr_src, int E) {
    int e = blockIdx.x * 256 + threadIdx.x;
    if (e >= E) return;
    int p = atomicAdd(&cursor[dst[e]], 1);
    csr_src[p] = src[e];
}

// ---------------------------------------------------------------------------
// MFMA GEMM: [nrows,256] x Wp(packed bf16) -> bf16 OUT [nrows,256] NODE-MAJOR
// (r8: reverted from head-major; cross-round comparison showed the node-major
// full-row gather (r1, 65us @ 3.44TB/s fill ceiling) beats every head-sliced
// L2-resident variant (r4/r6/r7: 99-130us) — full-row amortizes one load
// instr + one lexp chain over all 8 heads; lane redundancy is free).
// As staging XOR-swizzled (bank-conflict fix, r2) kept.
// ---------------------------------------------------------------------------
__global__ __launch_bounds__(256) void k_gemm_mfma(const void* __restrict__ Xv,
                                                   const int* __restrict__ xflag,
                                                   const u16* __restrict__ Wp,
                                                   u16* __restrict__ OUT, int nrows) {
    __shared__ u16 As[64 * 256];   // 32 KB
    const int t = threadIdx.x;
    const int w = t >> 6, L = t & 63;
    const int quad = (L >> 4) & 3;
    const int r0 = blockIdx.x * 64;
    const int nb = blockIdx.y * 8;
    const bool xf32 = (xflag != nullptr) && (*xflag == 1);

    short8* Asv = (short8*)As;
    short8 zero = {0, 0, 0, 0, 0, 0, 0, 0};
#pragma unroll
    for (int i = 0; i < 8; ++i) {
        int g = i * 256 + t;
        int row = g >> 5, cc = g & 31;
        int r = r0 + row;
        short8 val = zero;
        if (r < nrows) {
            if (xf32) {
                const f32x4* Xf4 = (const f32x4*)Xv;
                f32x4 lo = Xf4[(size_t)r * 64 + cc * 2];
                f32x4 hi = Xf4[(size_t)r * 64 + cc * 2 + 1];
                val[0] = (short)f2bf(lo[0]); val[1] = (short)f2bf(lo[1]);
                val[2] = (short)f2bf(lo[2]); val[3] = (short)f2bf(lo[3]);
                val[4] = (short)f2bf(hi[0]); val[5] = (short)f2bf(hi[1]);
                val[6] = (short)f2bf(hi[2]); val[7] = (short)f2bf(hi[3]);
            } else {
                val = ((const short8*)Xv)[(size_t)r * 32 + cc];
            }
        }
        Asv[cc * 64 + (row ^ (cc & 7))] = val;
    }

    const short8* Wv = (const short8*)Wp;
    short8 bf[2][8];
#pragma unroll
    for (int jn = 0; jn < 2; ++jn) {
        int nt = nb + w + jn * 4;
#pragma unroll
        for (int kt = 0; kt < 8; ++kt) bf[jn][kt] = Wv[(nt * 8 + kt) * 64 + L];
    }
    __syncthreads();

    f32x4 acc[4][2];
#pragma unroll
    for (int mi = 0; mi < 4; ++mi)
#pragma unroll
        for (int jn = 0; jn < 2; ++jn) acc[mi][jn] = (f32x4){0.f, 0.f, 0.f, 0.f};

#pragma unroll
    for (int kt = 0; kt < 8; ++kt) {
        const int ccr = kt * 4 + quad;
#pragma unroll
        for (int mi = 0; mi < 4; ++mi) {
            short8 af = Asv[ccr * 64 + ((mi * 16 + (L & 15)) ^ (ccr & 7))];
            acc[mi][0] = __builtin_amdgcn_mfma_f32_16x16x32_bf16(af, bf[0][kt], acc[mi][0], 0, 0, 0);
            acc[mi][1] = __builtin_amdgcn_mfma_f32_16x16x32_bf16(af, bf[1][kt], acc[mi][1], 0, 0, 0);
        }
    }

    const int colbase = blockIdx.y * 128;
#pragma unroll
    for (int mi = 0; mi < 4; ++mi) {
        int rb = r0 + mi * 16 + quad * 4;
#pragma unroll
        for (int jn = 0; jn < 2; ++jn) {
            int c = colbase + (w + jn * 4) * 16 + (L & 15);
#pragma unroll
            for (int reg = 0; reg < 4; ++reg) {
                int r = rb + reg;
                if (r < nrows) OUT[(size_t)r * 256 + c] = f2bf(acc[mi][jn][reg]);
            }
        }
    }
}

// MFMA GEMM layer 2: [nrows,256](bf16) x Wp2 -> bf16 [nrows,32]. BM=128, BN=32.
__global__ __launch_bounds__(256) void k_gemm_mfma32(const u16* __restrict__ Xb,
                                                     const u16* __restrict__ Wp,
                                                     u16* __restrict__ OUT, int nrows) {
    __shared__ u16 As[128 * 256];  // 64 KB
    const int t = threadIdx.x;
    const int w = t >> 6, L = t & 63;
    const int quad = (L >> 4) & 3;
    const int r0 = blockIdx.x * 128;
    const int mh = (w >> 1) * 64, nt = w & 1;

    const short8* Xv = (const short8*)Xb;
    short8* Asv = (short8*)As;
    short8 zero = {0, 0, 0, 0, 0, 0, 0, 0};
#pragma unroll
    for (int i = 0; i < 16; ++i) {
        int g = i * 256 + t;
        int row = g >> 5, cc = g & 31;
        int r = r0 + row;
        Asv[cc * 128 + (row ^ (cc & 7))] = (r < nrows) ? Xv[(size_t)r * 32 + cc] : zero;
    }

    const short8* Wv = (const short8*)Wp;
    short8 bf[8];
#pragma unroll
    for (int kt = 0; kt < 8; ++kt) bf[kt] = Wv[(nt * 8 + kt) * 64 + L];
    __syncthreads();

    f32x4 acc[4];
#pragma unroll
    for (int mi = 0; mi < 4; ++mi) acc[mi] = (f32x4){0.f, 0.f, 0.f, 0.f};

#pragma unroll
    for (int kt = 0; kt < 8; ++kt) {
        const int ccr = kt * 4 + quad;
#pragma unroll
        for (int mi = 0; mi < 4; ++mi) {
            short8 af = Asv[ccr * 128 + ((mh + mi * 16 + (L & 15)) ^ (ccr & 7))];
            acc[mi] = __builtin_amdgcn_mfma_f32_16x16x32_bf16(af, bf[kt], acc[mi], 0, 0, 0);
        }
    }

#pragma unroll
    for (int mi = 0; mi < 4; ++mi) {
        int rb = r0 + mh + mi * 16 + quad * 4;
        int c = nt * 16 + (L & 15);
#pragma unroll
        for (int reg = 0; reg < 4; ++reg) {
            int r = rb + reg;
            if (r < nrows) OUT[(size_t)r * 32 + c] = f2bf(acc[mi][reg]);
        }
    }
}

// attention logit dots (feat bf16 node-major, dwordx4 loads)
__global__ void k_elr8(const u16* __restrict__ featb, const float* __restrict__ al,
                       const float* __restrict__ ar, float* __restrict__ el,
                       float* __restrict__ er, int n) {
    int idx = blockIdx.x * 256 + threadIdx.x;
    if (idx >= n * 8) return;
    int node = idx >> 3, h = idx & 7;
    const u32v4* fu = (const u32v4*)((const u32*)featb + (size_t)node * 128 + h * 16);
    const float* A = al + h * 32;
    const float* B = ar + h * 32;
    float sl = 0.f, sr = 0.f;
#pragma unroll
    for (int j = 0; j < 4; ++j) {
        u32v4 w4 = fu[j];
#pragma unroll
        for (int k = 0; k < 4; ++k) {
            u32 w = (k == 0) ? w4.x : (k == 1) ? w4.y : (k == 2) ? w4.z : w4.w;
            float f0 = bflo(w), f1 = bfhi(w);
            int c = j * 8 + k * 2;
            sl += f0 * A[c] + f1 * A[c + 1];
            sr += f0 * B[c] + f1 * B[c + 1];
        }
    }
    el[idx] = sl;
    er[idx] = sr;
}

__global__ void k_elr1(const u16* __restrict__ featb, const float* __restrict__ al,
                       const float* __restrict__ ar, float* __restrict__ el,
                       float* __restrict__ er, int n) {
    int node = blockIdx.x * 256 + threadIdx.x;
    if (node >= n) return;
    const u32v4* fu = (const u32v4*)((const u32*)featb + (size_t)node * 16);
    float sl = 0.f, sr = 0.f;
#pragma unroll
    for (int j = 0; j < 4; ++j) {
        u32v4 w4 = fu[j];
#pragma unroll
        for (int k = 0; k < 4; ++k) {
            u32 w = (k == 0) ? w4.x : (k == 1) ? w4.y : (k == 2) ? w4.z : w4.w;
            float f0 = bflo(w), f1 = bfhi(w);
            int c = j * 8 + k * 2;
            sl += f0 * al[c] + f1 * al[c + 1];
            sr += f0 * ar[c] + f1 * ar[c + 1];
        }
    }
    el[node] = sl;
    er[node] = sr;
}

// ---------------------------------------------------------------------------
// fused softmax+gather: ONE WAVE PER NODE (64 lanes x dwordx2 = 4 cols/lane),
// software-pipelined 8-edge chunks (r8 = the MEASURED-BEST r1 kernel,
// verbatim: 65us @ 209MB / 3.44TB/s fill ceiling).
//
// Cross-round record: head-sliced L2-resident variants (r4/r6/r7) cut FETCH
// to 33MB but all landed 99-130us — per-(edge,head) issue cost dominates.
// Node-major full-row amortizes one 512B load + one lexp chain over all 8
// heads (lane redundancy is free in wave-instr terms); its 65us equals the
// fill ceiling for random 512B chunks, i.e. this structure's floor.
// ---------------------------------------------------------------------------
__global__ __launch_bounds__(256) void k_gather8(const int* __restrict__ rowptr,
                                                 const int* __restrict__ csr_src,
                                                 const float* __restrict__ el,
                                                 const float* __restrict__ er,
                                                 const u32v2* __restrict__ featb4,
                                                 const float* __restrict__ bias,
                                                 u32v2* __restrict__ xout4) {
    __shared__ __align__(16) float sAL[4][2][64];   // [wave][buf][h*8+e]
    __shared__ __align__(16) int   sSL[4][2][8];    // [wave][buf][e]
    const int t = threadIdx.x;
    const int wv = t >> 6;
    const int q = t & 63;            // owns cols 4q..4q+3, head h = q>>3
    const int d = blockIdx.x * 4 + wv;
    const int eL = q >> 3, hL = q & 7;   // producer role: edge eL, head hL
    const int b = rowptr[d], e = rowptr[d + 1];
    const int deg = e - b;
    const int nch = (deg + 7) >> 3;
    const float erA = er[d * 8 + hL];

    float (*AL)[64] = sAL[wv];
    int (*SL)[8] = sSL[wv];

    float a0 = 0.f, a1 = 0.f, a2 = 0.f, a3 = 0.f;
    float partial = 0.f;

    u32v2 fw[8], fw2[8];
    int csrP = 0, ncP = 0;
    float elP = 0.f;

    if (nch > 0) {
        // prologue: stage chunk 0 fully; issue chunk-1 csr + el
        const int nc0 = deg < 8 ? deg : 8;
        const int i0 = eL < nc0 ? eL : nc0 - 1;
        const int s0 = csr_src[b + i0];
        if (nch > 1) {
            const int r1 = deg - 8;
            ncP = r1 < 8 ? r1 : 8;
            const int i1 = eL < ncP ? eL : ncP - 1;
            csrP = csr_src[b + 8 + i1];
        }
        const float el0 = el[s0 * 8 + hL];
        if (hL == 0) SL[0][eL] = s0;
        const int4 sv0 = *(const int4*)&SL[0][0];
        const int4 sv1 = *(const int4*)&SL[0][4];
        fw[0] = featb4[sv0.x * 64 + q];
        fw[1] = featb4[sv0.y * 64 + q];
        fw[2] = featb4[sv0.z * 64 + q];
        fw[3] = featb4[sv0.w * 64 + q];
        fw[4] = featb4[sv1.x * 64 + q];
        fw[5] = featb4[sv1.y * 64 + q];
        fw[6] = featb4[sv1.z * 64 + q];
        fw[7] = featb4[sv1.w * 64 + q];
        const float ex0 = (eL < nc0) ? lexp(el0 + erA) : 0.f;
        partial += ex0;
        AL[0][hL * 8 + eL] = ex0;
        if (nch > 1) elP = el[csrP * 8 + hL];
    }

    for (int c = 0; c < nch; ++c) {
        const int cur = c & 1, nxt = cur ^ 1;

        // issue csr for chunk c+2 (2-deep so c+1's el issue never stalls)
        int csrF = 0, ncF = 0;
        if (c + 2 < nch) {
            const int r2 = deg - (c + 2) * 8;
            ncF = r2 < 8 ? r2 : 8;
            const int i2 = eL < ncF ? eL : ncF - 1;
            csrF = csr_src[b + (c + 2) * 8 + i2];
        }

        // stage chunk c+1: s-list -> LDS -> feat issues; alpha -> LDS
        if (c + 1 < nch) {
            if (hL == 0) SL[nxt][eL] = csrP;
            const int4 sv0 = *(const int4*)&SL[nxt][0];
            const int4 sv1 = *(const int4*)&SL[nxt][4];
            fw2[0] = featb4[sv0.x * 64 + q];
            fw2[1] = featb4[sv0.y * 64 + q];
            fw2[2] = featb4[sv0.z * 64 + q];
            fw2[3] = featb4[sv0.w * 64 + q];
            fw2[4] = featb4[sv1.x * 64 + q];
            fw2[5] = featb4[sv1.y * 64 + q];
            fw2[6] = featb4[sv1.z * 64 + q];
            fw2[7] = featb4[sv1.w * 64 + q];
            const float exN = (eL < ncP) ? lexp(elP + erA) : 0.f;
            partial += exN;
            AL[nxt][hL * 8 + eL] = exN;
        }

        // read alpha chunk c (broadcast ds_read_b128 x2, conflict-free)
        const int h8 = (q >> 3) * 8;
        const f32x4 A0 = *(const f32x4*)&AL[cur][h8];
        const f32x4 A1 = *(const f32x4*)&AL[cur][h8 + 4];

        // issue el for chunk c+2 (elP consumed above; safe to overwrite)
        if (c + 2 < nch) elP = el[csrF * 8 + hL];

        // FMA chunk c (feat issued one full chunk ago -> latency hidden)
#define GAT_EDGE(i, axv) { const u32v2 w_ = fw[i]; \
        a0 += bflo(w_.x) * (axv); a1 += bfhi(w_.x) * (axv); \
        a2 += bflo(w_.y) * (axv); a3 += bfhi(w_.y) * (axv); }
        GAT_EDGE(0, A0[0]) GAT_EDGE(1, A0[1]) GAT_EDGE(2, A0[2]) GAT_EDGE(3, A0[3])
        GAT_EDGE(4, A1[0]) GAT_EDGE(5, A1[1]) GAT_EDGE(6, A1[2]) GAT_EDGE(7, A1[3])
#undef GAT_EDGE

        // rotate pipeline state
#pragma unroll
        for (int i = 0; i < 8; ++i) fw[i] = fw2[i];
        csrP = csrF;
        ncP = ncF;
    }

    // denominator: reduce producer partials across eL (bits 3..5), then
    // fetch the consumer head's sum from lane (q>>3)
    float v = partial;
    v += __shfl_xor(v, 8);
    v += __shfl_xor(v, 16);
    v += __shfl_xor(v, 32);
    const float ssd = __shfl(v, q >> 3);

    const float rd = 1.f / (ssd + 1e-9f);
    const float4 bb = *(const float4*)&bias[4 * q];
    float v0 = a0 * rd + bb.x;
    float v1 = a1 * rd + bb.y;
    float v2 = a2 * rd + bb.z;
    float v3 = a3 * rd + bb.w;
    v0 = v0 > 0.f ? v0 : expm1f(v0);
    v1 = v1 > 0.f ? v1 : expm1f(v1);
    v2 = v2 > 0.f ? v2 : expm1f(v2);
    v3 = v3 > 0.f ? v3 : expm1f(v3);
    u32v2 o;
    o.x = (u32)f2bf(v0) | ((u32)f2bf(v1) << 16);
    o.y = (u32)f2bf(v2) | ((u32)f2bf(v3) << 16);
    xout4[(size_t)d * 64 + q] = o;
}

// layer-2 fused gather: 16 lanes/node x u32 (2 cols/lane), 4 nodes/wave.
__global__ __launch_bounds__(256) void k_gather1(const int* __restrict__ rowptr,
                                                 const int* __restrict__ csr_src,
                                                 const float* __restrict__ el,
                                                 const float* __restrict__ er,
                                                 const u32* __restrict__ featb2,
                                                 const float* __restrict__ bias,
                                                 void* __restrict__ out,
                                                 const int* __restrict__ flag, int n) {
    int t = threadIdx.x;
    int d = blockIdx.x * 16 + (t >> 4);
    int q = t & 15;           // owns cols 2q, 2q+1
    if (d >= n) return;
    int b = rowptr[d], e = rowptr[d + 1];
    float erd = er[d];
    float a0 = 0.f, a1 = 0.f, ssum = 0.f;
    int p = b;
    for (; p + 4 <= e; p += 4) {
        int s0 = csr_src[p], s1 = csr_src[p + 1], s2 = csr_src[p + 2], s3 = csr_src[p + 3];
        float e0 = lexp(el[s0] + erd);
        float e1 = lexp(el[s1] + erd);
        float e2 = lexp(el[s2] + erd);
        float e3 = lexp(el[s3] + erd);
        u32 w0 = featb2[(size_t)s0 * 16 + q];
        u32 w1 = featb2[(size_t)s1 * 16 + q];
        u32 w2 = featb2[(size_t)s2 * 16 + q];
        u32 w3 = featb2[(size_t)s3 * 16 + q];
        a0 += bflo(w0) * e0; a1 += bfhi(w0) * e0;
        a0 += bflo(w1) * e1; a1 += bfhi(w1) * e1;
        a0 += bflo(w2) * e2; a1 += bfhi(w2) * e2;
        a0 += bflo(w3) * e3; a1 += bfhi(w3) * e3;
        ssum += (e0 + e1) + (e2 + e3);
    }
    for (; p < e; ++p) {
        int s = csr_src[p];
        float ev = lexp(el[s] + erd);
        u32 w = featb2[(size_t)s * 16 + q];
        a0 += bflo(w) * ev;
        a1 += bfhi(w) * ev;
        ssum += ev;
    }
    float rd = 1.f / (ssum + 1e-9f);
    float v0 = a0 * rd + bias[2 * q];
    float v1 = a1 * rd + bias[2 * q + 1];
    if (*flag == 1) {
        f32x2 o = {v0, v1};
        ((f32x2*)out)[(size_t)d * 16 + q] = o;
    } else {
        ((u32*)out)[(size_t)d * 16 + q] = (u32)f2bf(v0) | ((u32)f2bf(v1) << 16);
    }
}

extern "C" void kernel_launch(void* const* d_in, const int* in_sizes, int n_in,
                              void* d_out, int out_size, void* d_ws, size_t ws_size,
                              hipStream_t stream) {
    const void* features = d_in[0];
    const int* src = (const int*)d_in[1];
    const int* dst = (const int*)d_in[2];

    char* ws = (char*)d_ws;
    size_t off = 0;
    auto carve = [&](size_t bytes) -> void* {
        void* p = ws + off;
        off = (off + bytes + 255) & ~(size_t)255;
        return p;
    };
    int*   flags = (int*)carve(64);
    float* pconv = (float*)carve(2048 * 4);
    u16*   Wp0 = (u16*)carve(65536 * 2);
    u16*   Wp1 = (u16*)carve(65536 * 2);
    u16*   Wp2 = (u16*)carve(8192 * 2);
    u16*   Xb    = (u16*)carve((size_t)NN * 256 * 2);  // bf16 hidden state
    u16*   featb = (u16*)carve((size_t)NN * 256 * 2);  // bf16 GEMM output
    float* el   = (float*)carve((size_t)NN * 8 * 4);
    float* er   = (float*)carve((size_t)NN * 8 * 4);
    int*   deg     = (int*)carve((size_t)NN * 4);
    int*   cursor  = (int*)carve((size_t)NN * 4);
    int*   rowptr  = (int*)carve((size_t)(NN + 1) * 4);
    int*   bsum    = (int*)carve(256 * 4);
    int*   csr_src = (int*)carve((size_t)NE * 4);
    if (off > ws_size) return;  // clean ws-too-small signature

    const int N = NN, E = NE;
    const int nscan = (N + 255) / 256;   // 196 <= 256

    DetectArgs da;
    const int din_idx[13] = {0, 3, 4, 5, 6, 7, 8, 9, 10, 11, 12, 13, 14};
    for (int j = 0; j < 13; ++j) {
        da.p[j] = (const u32*)d_in[din_idx[j]];
        int nw = in_sizes[din_idx[j]] / 2;
        da.nw[j] = nw > 512 ? 512 : nw;
    }
    k_detect<<<13, 256, 0, stream>>>(da, flags);

    // 9 small params -> fp32
    ConvArgs ca;
    const int psl[9] = {4, 5, 6, 8, 9, 10, 12, 13, 14};
    const int pfl[9] = {2, 3, 4, 6, 7, 8, 10, 11, 12};
    float* dsts[9];
    {
        size_t o = 0;
        for (int j = 0; j < 9; ++j) {
            dsts[j] = pconv + o;
            o += (size_t)in_sizes[psl[j]];
        }
    }
    for (int j = 0; j < 9; ++j) {
        ca.s[j] = d_in[psl[j]];
        ca.d[j] = dsts[j];
        ca.n[j] = in_sizes[psl[j]];
        ca.fi[j] = pfl[j];
    }
    k_convert<<<dim3(1, 9), 256, 0, stream>>>(ca, flags);
    float* al0f = dsts[0]; float* ar0f = dsts[1]; float* b0f = dsts[2];
    float* al1f = dsts[3]; float* ar1f = dsts[4]; float* b1f = dsts[5];
    float* al2f = dsts[6]; float* ar2f = dsts[7]; float* b2f = dsts[8];

    // W packing into B-frag order (once)
    k_wpack<<<32, 256, 0, stream>>>(d_in[3],  flags, 1, 256, Wp0, 8192);
    k_wpack<<<32, 256, 0, stream>>>(d_in[7],  flags, 5, 256, Wp1, 8192);
    k_wpack<<<4,  256, 0, stream>>>(d_in[11], flags, 9, 32,  Wp2, 1024);

    // CSR build (multi-block scan)
    hipMemsetAsync(deg, 0, (size_t)N * 4, stream);
    k_hist<<<(E + 255) / 256, 256, 0, stream>>>(dst, deg, E);
    k_scan_partial<<<nscan, 256, 0, stream>>>(deg, bsum, N);
    k_scan_bsum<<<1, 256, 0, stream>>>(bsum, nscan);
    k_scan_final<<<nscan, 256, 0, stream>>>(deg, bsum, rowptr, cursor, N);
    k_scatter<<<(E + 255) / 256, 256, 0, stream>>>(src, dst, cursor, csr_src, E);

    const dim3 ggrid((N + 63) / 64, 2);

    // ---------------- layer 0 (reads features directly, dtype via flag) ----
    k_gemm_mfma<<<ggrid, 256, 0, stream>>>(features, flags, Wp0, featb, N);
    k_elr8<<<(N * 8 + 255) / 256, 256, 0, stream>>>(featb, al0f, ar0f, el, er, N);
    k_gather8<<<N / 4, 256, 0, stream>>>(rowptr, csr_src, el, er,
                                         (const u32v2*)featb, b0f, (u32v2*)Xb);

    // ---------------- layer 1 ----------------
    k_gemm_mfma<<<ggrid, 256, 0, stream>>>(Xb, nullptr, Wp1, featb, N);
    k_elr8<<<(N * 8 + 255) / 256, 256, 0, stream>>>(featb, al1f, ar1f, el, er, N);
    k_gather8<<<N / 4, 256, 0, stream>>>(rowptr, csr_src, el, er,
                                         (const u32v2*)featb, b1f, (u32v2*)Xb);

    // ---------------- layer 2 (1 head, D=32) ----------------
    k_gemm_mfma32<<<(N + 127) / 128, 256, 0, stream>>>(Xb, Wp2, featb, N);
    k_elr1<<<(N + 255) / 256, 256, 0, stream>>>(featb, al2f, ar2f, el, er, N);
    k_gather1<<<(N + 15) / 16, 256, 0, stream>>>(rowptr, csr_src, el, er,
                                                 (const u32*)featb, b2f,
                                                 d_out, flags, N);
}

// Round 9
// 418.392 us; speedup vs baseline: 1.5818x; 1.0691x over previous
//
#include <hip/hip_runtime.h>

typedef unsigned short u16;
typedef unsigned int   u32;
typedef __attribute__((ext_vector_type(8))) short  short8;
typedef __attribute__((ext_vector_type(4))) float  f32x4;
typedef __attribute__((ext_vector_type(2))) float  f32x2;
typedef __attribute__((ext_vector_type(2))) unsigned int u32v2;
typedef __attribute__((ext_vector_type(4))) unsigned int u32v4;

#define NN 50000
#define NE 800000

__device__ __forceinline__ float bf2f(u16 b) { return __uint_as_float(((u32)b) << 16); }
__device__ __forceinline__ float bflo(u32 p) { return __uint_as_float(p << 16); }
__device__ __forceinline__ float bfhi(u32 p) { return __uint_as_float(p & 0xffff0000u); }
__device__ __forceinline__ u16 f2bf(float f) {
    u32 u = __float_as_uint(f);
    u32 r = u + 0x7fffu + ((u >> 16) & 1u);
    return (u16)(r >> 16);
}
// leaky-relu + clamped exp (clamp is identity for this data's logit range)
__device__ __forceinline__ float lexp(float v) {
    v = fmaxf(v, 0.2f * v);
    return __expf(fminf(v, 60.f));
}

// block-wide dtype detect (0=bf16, 1=fp32, 2=all-zero) from a 512-word
// prefix; result valid in ALL threads (reduction ends with syncthreads).
__device__ __forceinline__ int block_detect(const u32* x, int n, int* sh, int* sz) {
    int t = threadIdx.x;
    int hits = 0, nz = 0;
    for (int i = t; i < n; i += 256) {
        u32 w = x[i];
        if (w) {
            ++nz;
            u32 e = (w >> 7) & 0xffu;
            if (e >= 100 && e <= 150) ++hits;
        }
    }
    sh[t] = hits; sz[t] = nz;
    __syncthreads();
    for (int ofs = 128; ofs > 0; ofs >>= 1) {
        if (t < ofs) { sh[t] += sh[t + ofs]; sz[t] += sz[t + ofs]; }
        __syncthreads();
    }
    return (sz[0] == 0) ? 2 : ((sh[0] * 2 >= sz[0]) ? 0 : 1);
}

// ---------------------------------------------------------------------------
// k_prep (r9): detect(13) + convert(9) + wpack x3 merged into ONE launch.
// convert/wpack blocks self-detect their source tensor's dtype (same prefix,
// same rule -> identical result, no inter-block dependency). flags[] is
// still written by blocks 0..12 for downstream consumers (gemm, gather1).
// ---------------------------------------------------------------------------
struct PrepArgs {
    const u32* dp[13]; int dnw[13];                 // detect
    const void* cs[9]; float* cd[9]; int cn[9];     // convert (n <= 256)
    const void* wsrc[3]; u16* wdst[3]; int wN[3]; int wchunks[3];  // wpack
};

__global__ __launch_bounds__(256) void k_prep(PrepArgs a, int* flags) {
    __shared__ int sh[256], sz[256];
    const int bid = blockIdx.x;
    const int t = threadIdx.x;
    if (bid < 13) {
        int f = block_detect(a.dp[bid], a.dnw[bid], sh, sz);
        if (t == 0) flags[bid] = f;
    } else if (bid < 22) {
        const int j = bid - 13;
        int nw = a.cn[j] / 2; if (nw > 512) nw = 512;
        const int fl = block_detect((const u32*)a.cs[j], nw, sh, sz);
        if (t < a.cn[j]) {
            float v = 0.f;
            if (fl == 1) v = ((const float*)a.cs[j])[t];
            else if (fl == 0) v = bf2f(((const u16*)a.cs[j])[t]);
            a.cd[j][t] = v;
        }
    } else {
        int wj, base;
        if (bid < 54)      { wj = 0; base = 22; }
        else if (bid < 86) { wj = 1; base = 54; }
        else               { wj = 2; base = 86; }
        const void* Wsrc = a.wsrc[wj];
        const int fl = block_detect((const u32*)Wsrc, 512, sh, sz);
        const int id = (bid - base) * 256 + t;
        if (id < a.wchunks[wj]) {
            const int L = id & 63, kt = (id >> 6) & 7, nt = id >> 9;
            const int col = nt * 16 + (L & 15);
            const int krow = kt * 32 + ((L >> 4) & 3) * 8;
            const bool isf32 = (fl == 1);
            const int N = a.wN[wj];
            u16* Wp = a.wdst[wj];
#pragma unroll
            for (int j2 = 0; j2 < 8; ++j2) {
                int s = (krow + j2) * N + col;
                Wp[id * 8 + j2] = isf32 ? f2bf(((const float*)Wsrc)[s])
                                        : ((const u16*)Wsrc)[s];
            }
        }
    }
}

// ---------------------------------------------------------------------------
// CSR build (graph static across layers) — 3-phase multi-block scan
// ---------------------------------------------------------------------------
__global__ void k_hist(const int* __restrict__ dst, int* __restrict__ deg, int E) {
    int e = blockIdx.x * 256 + threadIdx.x;
    if (e < E) atomicAdd(&deg[dst[e]], 1);
}

__global__ __launch_bounds__(256) void k_scan_partial(const int* __restrict__ deg,
                                                      int* __restrict__ bsum, int n) {
    __shared__ int red[256];
    int t = threadIdx.x;
    int i = blockIdx.x * 256 + t;
    red[t] = (i < n) ? deg[i] : 0;
    __syncthreads();
    for (int ofs = 128; ofs > 0; ofs >>= 1) {
        if (t < ofs) red[t] += red[t + ofs];
        __syncthreads();
    }
    if (t == 0) bsum[blockIdx.x] = red[0];
}

__global__ __launch_bounds__(256) void k_scan_bsum(int* __restrict__ bsum, int nb) {
    __shared__ int s[256];
    int t = threadIdx.x;
    int v = (t < nb) ? bsum[t] : 0;
    s[t] = v;
    __syncthreads();
    for (int ofs = 1; ofs < 256; ofs <<= 1) {
        int x = (t >= ofs) ? s[t - ofs] : 0;
        __syncthreads();
        s[t] += x;
        __syncthreads();
    }
    if (t < nb) bsum[t] = s[t] - v;   // exclusive
}

__global__ __launch_bounds__(256) void k_scan_final(const int* __restrict__ deg,
                                                    const int* __restrict__ bsum,
                                                    int* __restrict__ rowptr,
                                                    int* __restrict__ cursor, int n) {
    __shared__ int s[256];
    int t = threadIdx.x;
    int i = blockIdx.x * 256 + t;
    int v = (i < n) ? deg[i] : 0;
    s[t] = v;
    __syncthreads();
    for (int ofs = 1; ofs < 256; ofs <<= 1) {
        int x = (t >= ofs) ? s[t - ofs] : 0;
        __syncthreads();
        s[t] += x;
        __syncthreads();
    }
    int excl = bsum[blockIdx.x] + s[t] - v;
    if (i < n) {
        rowptr[i] = excl;
        cursor[i] = excl;
        if (i == n - 1) rowptr[n] = excl + v;
    }
}

__global__ void k_scatter(const int* __restrict__ src, const int* __restrict__ dst,
                          int* __restrict__ cursor, int* __restrict__ csr_src, int E) {
    int e = blockIdx.x * 256 + threadIdx.x;
    if (e >= E) return;
    int p = atomicAdd(&cursor[dst[e]], 1);
    csr_src[p] = src[e];
}

// ---------------------------------------------------------------------------
// MFMA GEMM (r9: FULL-WIDTH): [nrows,256] x Wp -> bf16 OUT [nrows,256],
// 512 threads / 8 waves per block, grid (nrows/64). Each block computes all
// 256 output cols -> X staged ONCE (25.6MB total vs 51.2 with the old
// 2-y-block grid). Wave w covers nt = w and w+8. W refetch 128KB/block is
// L2-resident. As staging XOR-swizzled (bank-conflict fix, r2).
// ---------------------------------------------------------------------------
__global__ __launch_bounds__(512) void k_gemm_mfma(const void* __restrict__ Xv,
                                                   const int* __restrict__ xflag,
                                                   const u16* __restrict__ Wp,
                                                   u16* __restrict__ OUT, int nrows) {
    __shared__ u16 As[64 * 256];   // 32 KB
    const int t = threadIdx.x;
    const int w = t >> 6, L = t & 63;
    const int quad = (L >> 4) & 3;
    const int r0 = blockIdx.x * 64;
    const bool xf32 = (xflag != nullptr) && (*xflag == 1);

    short8* Asv = (short8*)As;
    short8 zero = {0, 0, 0, 0, 0, 0, 0, 0};
#pragma unroll
    for (int i = 0; i < 4; ++i) {
        int g = i * 512 + t;
        int row = g >> 5, cc = g & 31;
        int r = r0 + row;
        short8 val = zero;
        if (r < nrows) {
            if (xf32) {
                const f32x4* Xf4 = (const f32x4*)Xv;
                f32x4 lo = Xf4[(size_t)r * 64 + cc * 2];
                f32x4 hi = Xf4[(size_t)r * 64 + cc * 2 + 1];
                val[0] = (short)f2bf(lo[0]); val[1] = (short)f2bf(lo[1]);
                val[2] = (short)f2bf(lo[2]); val[3] = (short)f2bf(lo[3]);
                val[4] = (short)f2bf(hi[0]); val[5] = (short)f2bf(hi[1]);
                val[6] = (short)f2bf(hi[2]); val[7] = (short)f2bf(hi[3]);
            } else {
                val = ((const short8*)Xv)[(size_t)r * 32 + cc];
            }
        }
        Asv[cc * 64 + (row ^ (cc & 7))] = val;
    }

    const short8* Wv = (const short8*)Wp;
    short8 bf[2][8];
#pragma unroll
    for (int jn = 0; jn < 2; ++jn) {
        int nt = w + jn * 8;
#pragma unroll
        for (int kt = 0; kt < 8; ++kt) bf[jn][kt] = Wv[(nt * 8 + kt) * 64 + L];
    }
    __syncthreads();

    f32x4 acc[4][2];
#pragma unroll
    for (int mi = 0; mi < 4; ++mi)
#pragma unroll
        for (int jn = 0; jn < 2; ++jn) acc[mi][jn] = (f32x4){0.f, 0.f, 0.f, 0.f};

#pragma unroll
    for (int kt = 0; kt < 8; ++kt) {
        const int ccr = kt * 4 + quad;
#pragma unroll
        for (int mi = 0; mi < 4; ++mi) {
            short8 af = Asv[ccr * 64 + ((mi * 16 + (L & 15)) ^ (ccr & 7))];
            acc[mi][0] = __builtin_amdgcn_mfma_f32_16x16x32_bf16(af, bf[0][kt], acc[mi][0], 0, 0, 0);
            acc[mi][1] = __builtin_amdgcn_mfma_f32_16x16x32_bf16(af, bf[1][kt], acc[mi][1], 0, 0, 0);
        }
    }

#pragma unroll
    for (int mi = 0; mi < 4; ++mi) {
        int rb = r0 + mi * 16 + quad * 4;
#pragma unroll
        for (int jn = 0; jn < 2; ++jn) {
            int c = (w + jn * 8) * 16 + (L & 15);
#pragma unroll
            for (int reg = 0; reg < 4; ++reg) {
                int r = rb + reg;
                if (r < nrows) OUT[(size_t)r * 256 + c] = f2bf(acc[mi][jn][reg]);
            }
        }
    }
}

// MFMA GEMM layer 2: [nrows,256](bf16) x Wp2 -> bf16 [nrows,32]. BM=128, BN=32.
__global__ __launch_bounds__(256) void k_gemm_mfma32(const u16* __restrict__ Xb,
                                                     const u16* __restrict__ Wp,
                                                     u16* __restrict__ OUT, int nrows) {
    __shared__ u16 As[128 * 256];  // 64 KB
    const int t = threadIdx.x;
    const int w = t >> 6, L = t & 63;
    const int quad = (L >> 4) & 3;
    const int r0 = blockIdx.x * 128;
    const int mh = (w >> 1) * 64, nt = w & 1;

    const short8* Xv = (const short8*)Xb;
    short8* Asv = (short8*)As;
    short8 zero = {0, 0, 0, 0, 0, 0, 0, 0};
#pragma unroll
    for (int i = 0; i < 16; ++i) {
        int g = i * 256 + t;
        int row = g >> 5, cc = g & 31;
        int r = r0 + row;
        Asv[cc * 128 + (row ^ (cc & 7))] = (r < nrows) ? Xv[(size_t)r * 32 + cc] : zero;
    }

    const short8* Wv = (const short8*)Wp;
    short8 bf[8];
#pragma unroll
    for (int kt = 0; kt < 8; ++kt) bf[kt] = Wv[(nt * 8 + kt) * 64 + L];
    __syncthreads();

    f32x4 acc[4];
#pragma unroll
    for (int mi = 0; mi < 4; ++mi) acc[mi] = (f32x4){0.f, 0.f, 0.f, 0.f};

#pragma unroll
    for (int kt = 0; kt < 8; ++kt) {
        const int ccr = kt * 4 + quad;
#pragma unroll
        for (int mi = 0; mi < 4; ++mi) {
            short8 af = Asv[ccr * 128 + ((mh + mi * 16 + (L & 15)) ^ (ccr & 7))];
            acc[mi] = __builtin_amdgcn_mfma_f32_16x16x32_bf16(af, bf[kt], acc[mi], 0, 0, 0);
        }
    }

#pragma unroll
    for (int mi = 0; mi < 4; ++mi) {
        int rb = r0 + mh + mi * 16 + quad * 4;
        int c = nt * 16 + (L & 15);
#pragma unroll
        for (int reg = 0; reg < 4; ++reg) {
            int r = rb + reg;
            if (r < nrows) OUT[(size_t)r * 32 + c] = f2bf(acc[mi][reg]);
        }
    }
}

// attention logit dots (feat bf16 node-major, dwordx4 loads)
__global__ void k_elr8(const u16* __restrict__ featb, const float* __restrict__ al,
                       const float* __restrict__ ar, float* __restrict__ el,
                       float* __restrict__ er, int n) {
    int idx = blockIdx.x * 256 + threadIdx.x;
    if (idx >= n * 8) return;
    int node = idx >> 3, h = idx & 7;
    const u32v4* fu = (const u32v4*)((const u32*)featb + (size_t)node * 128 + h * 16);
    const float* A = al + h * 32;
    const float* B = ar + h * 32;
    float sl = 0.f, sr = 0.f;
#pragma unroll
    for (int j = 0; j < 4; ++j) {
        u32v4 w4 = fu[j];
#pragma unroll
        for (int k = 0; k < 4; ++k) {
            u32 w = (k == 0) ? w4.x : (k == 1) ? w4.y : (k == 2) ? w4.z : w4.w;
            float f0 = bflo(w), f1 = bfhi(w);
            int c = j * 8 + k * 2;
            sl += f0 * A[c] + f1 * A[c + 1];
            sr += f0 * B[c] + f1 * B[c + 1];
        }
    }
    el[idx] = sl;
    er[idx] = sr;
}

__global__ void k_elr1(const u16* __restrict__ featb, const float* __restrict__ al,
                       const float* __restrict__ ar, float* __restrict__ el,
                       float* __restrict__ er, int n) {
    int node = blockIdx.x * 256 + threadIdx.x;
    if (node >= n) return;
    const u32v4* fu = (const u32v4*)((const u32*)featb + (size_t)node * 16);
    float sl = 0.f, sr = 0.f;
#pragma unroll
    for (int j = 0; j < 4; ++j) {
        u32v4 w4 = fu[j];
#pragma unroll
        for (int k = 0; k < 4; ++k) {
            u32 w = (k == 0) ? w4.x : (k == 1) ? w4.y : (k == 2) ? w4.z : w4.w;
            float f0 = bflo(w), f1 = bfhi(w);
            int c = j * 8 + k * 2;
            sl += f0 * al[c] + f1 * al[c + 1];
            sr += f0 * ar[c] + f1 * ar[c + 1];
        }
    }
    el[node] = sl;
    er[node] = sr;
}

// ---------------------------------------------------------------------------
// fused softmax+gather: ONE WAVE PER NODE (64 lanes x dwordx2 = 4 cols/lane),
// software-pipelined 8-edge chunks (the MEASURED-BEST r1 kernel, verbatim:
// 65.5us @ 209MB / 3.67TB/s = the random-512B-chunk L3->L2 fill ceiling;
// head-sliced L2-resident variants cut FETCH to 33MB but paid more in
// per-(edge,head) issue cost — 99-130us. Do not re-litigate without a new
// mechanism for BOTH traffic and issue amortization.)
// ---------------------------------------------------------------------------
__global__ __launch_bounds__(256) void k_gather8(const int* __restrict__ rowptr,
                                                 const int* __restrict__ csr_src,
                                                 const float* __restrict__ el,
                                                 const float* __restrict__ er,
                                                 const u32v2* __restrict__ featb4,
                                                 const float* __restrict__ bias,
                                                 u32v2* __restrict__ xout4) {
    __shared__ __align__(16) float sAL[4][2][64];   // [wave][buf][h*8+e]
    __shared__ __align__(16) int   sSL[4][2][8];    // [wave][buf][e]
    const int t = threadIdx.x;
    const int wv = t >> 6;
    const int q = t & 63;            // owns cols 4q..4q+3, head h = q>>3
    const int d = blockIdx.x * 4 + wv;
    const int eL = q >> 3, hL = q & 7;   // producer role: edge eL, head hL
    const int b = rowptr[d], e = rowptr[d + 1];
    const int deg = e - b;
    const int nch = (deg + 7) >> 3;
    const float erA = er[d * 8 + hL];

    float (*AL)[64] = sAL[wv];
    int (*SL)[8] = sSL[wv];

    float a0 = 0.f, a1 = 0.f, a2 = 0.f, a3 = 0.f;
    float partial = 0.f;

    u32v2 fw[8], fw2[8];
    int csrP = 0, ncP = 0;
    float elP = 0.f;

    if (nch > 0) {
        // prologue: stage chunk 0 fully; issue chunk-1 csr + el
        const int nc0 = deg < 8 ? deg : 8;
        const int i0 = eL < nc0 ? eL : nc0 - 1;
        const int s0 = csr_src[b + i0];
        if (nch > 1) {
            const int r1 = deg - 8;
            ncP = r1 < 8 ? r1 : 8;
            const int i1 = eL < ncP ? eL : ncP - 1;
            csrP = csr_src[b + 8 + i1];
        }
        const float el0 = el[s0 * 8 + hL];
        if (hL == 0) SL[0][eL] = s0;
        const int4 sv0 = *(const int4*)&SL[0][0];
        const int4 sv1 = *(const int4*)&SL[0][4];
        fw[0] = featb4[sv0.x * 64 + q];
        fw[1] = featb4[sv0.y * 64 + q];
        fw[2] = featb4[sv0.z * 64 + q];
        fw[3] = featb4[sv0.w * 64 + q];
        fw[4] = featb4[sv1.x * 64 + q];
        fw[5] = featb4[sv1.y * 64 + q];
        fw[6] = featb4[sv1.z * 64 + q];
        fw[7] = featb4[sv1.w * 64 + q];
        const float ex0 = (eL < nc0) ? lexp(el0 + erA) : 0.f;
        partial += ex0;
        AL[0][hL * 8 + eL] = ex0;
        if (nch > 1) elP = el[csrP * 8 + hL];
    }

    for (int c = 0; c < nch; ++c) {
        const int cur = c & 1, nxt = cur ^ 1;

        // issue csr for chunk c+2 (2-deep so c+1's el issue never stalls)
        int csrF = 0, ncF = 0;
        if (c + 2 < nch) {
            const int r2 = deg - (c + 2) * 8;
            ncF = r2 < 8 ? r2 : 8;
            const int i2 = eL < ncF ? eL : ncF - 1;
            csrF = csr_src[b + (c + 2) * 8 + i2];
        }

        // stage chunk c+1: s-list -> LDS -> feat issues; alpha -> LDS
        if (c + 1 < nch) {
            if (hL == 0) SL[nxt][eL] = csrP;
            const int4 sv0 = *(const int4*)&SL[nxt][0];
            const int4 sv1 = *(const int4*)&SL[nxt][4];
            fw2[0] = featb4[sv0.x * 64 + q];
            fw2[1] = featb4[sv0.y * 64 + q];
            fw2[2] = featb4[sv0.z * 64 + q];
            fw2[3] = featb4[sv0.w * 64 + q];
            fw2[4] = featb4[sv1.x * 64 + q];
            fw2[5] = featb4[sv1.y * 64 + q];
            fw2[6] = featb4[sv1.z * 64 + q];
            fw2[7] = featb4[sv1.w * 64 + q];
            const float exN = (eL < ncP) ? lexp(elP + erA) : 0.f;
            partial += exN;
            AL[nxt][hL * 8 + eL] = exN;
        }

        // read alpha chunk c (broadcast ds_read_b128 x2, conflict-free)
        const int h8 = (q >> 3) * 8;
        const f32x4 A0 = *(const f32x4*)&AL[cur][h8];
        const f32x4 A1 = *(const f32x4*)&AL[cur][h8 + 4];

        // issue el for chunk c+2 (elP consumed above; safe to overwrite)
        if (c + 2 < nch) elP = el[csrF * 8 + hL];

        // FMA chunk c (feat issued one full chunk ago -> latency hidden)
#define GAT_EDGE(i, axv) { const u32v2 w_ = fw[i]; \
        a0 += bflo(w_.x) * (axv); a1 += bfhi(w_.x) * (axv); \
        a2 += bflo(w_.y) * (axv); a3 += bfhi(w_.y) * (axv); }
        GAT_EDGE(0, A0[0]) GAT_EDGE(1, A0[1]) GAT_EDGE(2, A0[2]) GAT_EDGE(3, A0[3])
        GAT_EDGE(4, A1[0]) GAT_EDGE(5, A1[1]) GAT_EDGE(6, A1[2]) GAT_EDGE(7, A1[3])
#undef GAT_EDGE

        // rotate pipeline state
#pragma unroll
        for (int i = 0; i < 8; ++i) fw[i] = fw2[i];
        csrP = csrF;
        ncP = ncF;
    }

    // denominator: reduce producer partials across eL (bits 3..5), then
    // fetch the consumer head's sum from lane (q>>3)
    float v = partial;
    v += __shfl_xor(v, 8);
    v += __shfl_xor(v, 16);
    v += __shfl_xor(v, 32);
    const float ssd = __shfl(v, q >> 3);

    const float rd = 1.f / (ssd + 1e-9f);
    const float4 bb = *(const float4*)&bias[4 * q];
    float v0 = a0 * rd + bb.x;
    float v1 = a1 * rd + bb.y;
    float v2 = a2 * rd + bb.z;
    float v3 = a3 * rd + bb.w;
    v0 = v0 > 0.f ? v0 : expm1f(v0);
    v1 = v1 > 0.f ? v1 : expm1f(v1);
    v2 = v2 > 0.f ? v2 : expm1f(v2);
    v3 = v3 > 0.f ? v3 : expm1f(v3);
    u32v2 o;
    o.x = (u32)f2bf(v0) | ((u32)f2bf(v1) << 16);
    o.y = (u32)f2bf(v2) | ((u32)f2bf(v3) << 16);
    xout4[(size_t)d * 64 + q] = o;
}

// layer-2 fused gather: 16 lanes/node x u32 (2 cols/lane), 4 nodes/wave.
__global__ __launch_bounds__(256) void k_gather1(const int* __restrict__ rowptr,
                                                 const int* __restrict__ csr_src,
                                                 const float* __restrict__ el,
                                                 const float* __restrict__ er,
                                                 const u32* __restrict__ featb2,
                                                 const float* __restrict__ bias,
                                                 void* __restrict__ out,
                                                 const int* __restrict__ flag, int n) {
    int t = threadIdx.x;
    int d = blockIdx.x * 16 + (t >> 4);
    int q = t & 15;           // owns cols 2q, 2q+1
    if (d >= n) return;
    int b = rowptr[d], e = rowptr[d + 1];
    float erd = er[d];
    float a0 = 0.f, a1 = 0.f, ssum = 0.f;
    int p = b;
    for (; p + 4 <= e; p += 4) {
        int s0 = csr_src[p], s1 = csr_src[p + 1], s2 = csr_src[p + 2], s3 = csr_src[p + 3];
        float e0 = lexp(el[s0] + erd);
        float e1 = lexp(el[s1] + erd);
        float e2 = lexp(el[s2] + erd);
        float e3 = lexp(el[s3] + erd);
        u32 w0 = featb2[(size_t)s0 * 16 + q];
        u32 w1 = featb2[(size_t)s1 * 16 + q];
        u32 w2 = featb2[(size_t)s2 * 16 + q];
        u32 w3 = featb2[(size_t)s3 * 16 + q];
        a0 += bflo(w0) * e0; a1 += bfhi(w0) * e0;
        a0 += bflo(w1) * e1; a1 += bfhi(w1) * e1;
        a0 += bflo(w2) * e2; a1 += bfhi(w2) * e2;
        a0 += bflo(w3) * e3; a1 += bfhi(w3) * e3;
        ssum += (e0 + e1) + (e2 + e3);
    }
    for (; p < e; ++p) {
        int s = csr_src[p];
        float ev = lexp(el[s] + erd);
        u32 w = featb2[(size_t)s * 16 + q];
        a0 += bflo(w) * ev;
        a1 += bfhi(w) * ev;
        ssum += ev;
    }
    float rd = 1.f / (ssum + 1e-9f);
    float v0 = a0 * rd + bias[2 * q];
    float v1 = a1 * rd + bias[2 * q + 1];
    if (*flag == 1) {
        f32x2 o = {v0, v1};
        ((f32x2*)out)[(size_t)d * 16 + q] = o;
    } else {
        ((u32*)out)[(size_t)d * 16 + q] = (u32)f2bf(v0) | ((u32)f2bf(v1) << 16);
    }
}

extern "C" void kernel_launch(void* const* d_in, const int* in_sizes, int n_in,
                              void* d_out, int out_size, void* d_ws, size_t ws_size,
                              hipStream_t stream) {
    const void* features = d_in[0];
    const int* src = (const int*)d_in[1];
    const int* dst = (const int*)d_in[2];

    char* ws = (char*)d_ws;
    size_t off = 0;
    auto carve = [&](size_t bytes) -> void* {
        void* p = ws + off;
        off = (off + bytes + 255) & ~(size_t)255;
        return p;
    };
    int*   flags = (int*)carve(64);
    float* pconv = (float*)carve(2048 * 4);
    u16*   Wp0 = (u16*)carve(65536 * 2);
    u16*   Wp1 = (u16*)carve(65536 * 2);
    u16*   Wp2 = (u16*)carve(8192 * 2);
    u16*   Xb    = (u16*)carve((size_t)NN * 256 * 2);  // bf16 hidden state
    u16*   featb = (u16*)carve((size_t)NN * 256 * 2);  // bf16 GEMM output
    float* el   = (float*)carve((size_t)NN * 8 * 4);
    float* er   = (float*)carve((size_t)NN * 8 * 4);
    int*   deg     = (int*)carve((size_t)NN * 4);
    int*   cursor  = (int*)carve((size_t)NN * 4);
    int*   rowptr  = (int*)carve((size_t)(NN + 1) * 4);
    int*   bsum    = (int*)carve(256 * 4);
    int*   csr_src = (int*)carve((size_t)NE * 4);
    if (off > ws_size) return;  // clean ws-too-small signature

    const int N = NN, E = NE;
    const int nscan = (N + 255) / 256;   // 196 <= 256

    // ---- merged prep: detect(13) + convert(9) + wpack x3, ONE launch ----
    PrepArgs pa;
    const int din_idx[13] = {0, 3, 4, 5, 6, 7, 8, 9, 10, 11, 12, 13, 14};
    for (int j = 0; j < 13; ++j) {
        pa.dp[j] = (const u32*)d_in[din_idx[j]];
        int nw = in_sizes[din_idx[j]] / 2;
        pa.dnw[j] = nw > 512 ? 512 : nw;
    }
    const int psl[9] = {4, 5, 6, 8, 9, 10, 12, 13, 14};
    float* dsts[9];
    {
        size_t o = 0;
        for (int j = 0; j < 9; ++j) {
            dsts[j] = pconv + o;
            o += (size_t)in_sizes[psl[j]];
        }
    }
    for (int j = 0; j < 9; ++j) {
        pa.cs[j] = d_in[psl[j]];
        pa.cd[j] = dsts[j];
        pa.cn[j] = in_sizes[psl[j]];
    }
    pa.wsrc[0] = d_in[3];  pa.wdst[0] = Wp0; pa.wN[0] = 256; pa.wchunks[0] = 8192;
    pa.wsrc[1] = d_in[7];  pa.wdst[1] = Wp1; pa.wN[1] = 256; pa.wchunks[1] = 8192;
    pa.wsrc[2] = d_in[11]; pa.wdst[2] = Wp2; pa.wN[2] = 32;  pa.wchunks[2] = 1024;
    k_prep<<<90, 256, 0, stream>>>(pa, flags);
    float* al0f = dsts[0]; float* ar0f = dsts[1]; float* b0f = dsts[2];
    float* al1f = dsts[3]; float* ar1f = dsts[4]; float* b1f = dsts[5];
    float* al2f = dsts[6]; float* ar2f = dsts[7]; float* b2f = dsts[8];

    // CSR build (multi-block scan)
    hipMemsetAsync(deg, 0, (size_t)N * 4, stream);
    k_hist<<<(E + 255) / 256, 256, 0, stream>>>(dst, deg, E);
    k_scan_partial<<<nscan, 256, 0, stream>>>(deg, bsum, N);
    k_scan_bsum<<<1, 256, 0, stream>>>(bsum, nscan);
    k_scan_final<<<nscan, 256, 0, stream>>>(deg, bsum, rowptr, cursor, N);
    k_scatter<<<(E + 255) / 256, 256, 0, stream>>>(src, dst, cursor, csr_src, E);

    const int ggrid = (N + 63) / 64;   // full-width gemm: 512 threads/block

    // ---------------- layer 0 (reads features directly, dtype via flag) ----
    k_gemm_mfma<<<ggrid, 512, 0, stream>>>(features, flags, Wp0, featb, N);
    k_elr8<<<(N * 8 + 255) / 256, 256, 0, stream>>>(featb, al0f, ar0f, el, er, N);
    k_gather8<<<N / 4, 256, 0, stream>>>(rowptr, csr_src, el, er,
                                         (const u32v2*)featb, b0f, (u32v2*)Xb);

    // ---------------- layer 1 ----------------
    k_gemm_mfma<<<ggrid, 512, 0, stream>>>(Xb, nullptr, Wp1, featb, N);
    k_elr8<<<(N * 8 + 255) / 256, 256, 0, stream>>>(featb, al1f, ar1f, el, er, N);
    k_gather8<<<N / 4, 256, 0, stream>>>(rowptr, csr_src, el, er,
                                         (const u32v2*)featb, b1f, (u32v2*)Xb);

    // ---------------- layer 2 (1 head, D=32) ----------------
    k_gemm_mfma32<<<(N + 127) / 128, 256, 0, stream>>>(Xb, Wp2, featb, N);
    k_elr1<<<(N + 255) / 256, 256, 0, stream>>>(featb, al2f, ar2f, el, er, N);
    k_gather1<<<(N + 15) / 16, 256, 0, stream>>>(rowptr, csr_src, el, er,
                                                 (const u32*)featb, b2f,
                                                 d_out, flags, N);
}